// Round 1
// baseline (16797.328 us; speedup 1.0000x reference)
//
#include <hip/hip_runtime.h>
#include <hip/hip_bf16.h>

#define D_MODEL 768
#define SEQ     1024
#define NB      8
#define NHEAD   12
#define HS      64
#define NLAYER  4
#define DFF     3072
#define NCLS    16
#define MROWS   (NB*SEQ)   // 8192

// ---------------------------------------------------------------- embedding
__global__ __launch_bounds__(256) void embed_kernel(
    const int* __restrict__ x, const float* __restrict__ tok,
    const float* __restrict__ pos, float* __restrict__ h)
{
    int row = blockIdx.x;           // 0..8191  (b*S + s)
    int s   = row & (SEQ - 1);
    int t   = threadIdx.x;
    int id  = x[row];
    const float* te = tok + (size_t)id * D_MODEL;
    const float* pe = pos + (size_t)s  * D_MODEL;
    float* hr = h + (size_t)row * D_MODEL;
    for (int d = t; d < D_MODEL; d += 256) hr[d] = te[d] + pe[d];
}

// ---------------------------------------------------------------- layernorm
// one block per output row; input row = r*row_stride + row_offset
__global__ __launch_bounds__(256) void ln_kernel(
    const float* __restrict__ in, const float* __restrict__ w,
    const float* __restrict__ b, float* __restrict__ out,
    int row_stride, int row_offset)
{
    __shared__ float red[256];
    int r = blockIdx.x;
    const float* xr = in + (size_t)(r * row_stride + row_offset) * D_MODEL;
    float* yr = out + (size_t)r * D_MODEL;
    int t = threadIdx.x;
    float v0 = xr[t], v1 = xr[t + 256], v2 = xr[t + 512];
    red[t] = v0 + v1 + v2; __syncthreads();
    for (int off = 128; off; off >>= 1) { if (t < off) red[t] += red[t + off]; __syncthreads(); }
    float mu = red[0] * (1.f / D_MODEL);
    __syncthreads();
    float d0 = v0 - mu, d1 = v1 - mu, d2 = v2 - mu;
    red[t] = d0*d0 + d1*d1 + d2*d2; __syncthreads();
    for (int off = 128; off; off >>= 1) { if (t < off) red[t] += red[t + off]; __syncthreads(); }
    float rstd = rsqrtf(red[0] * (1.f / D_MODEL) + 1e-5f);
    yr[t]       = d0 * rstd * w[t]       + b[t];
    yr[t + 256] = d1 * rstd * w[t + 256] + b[t + 256];
    yr[t + 512] = d2 * rstd * w[t + 512] + b[t + 512];
}

// ---------------------------------------------------------------- GEMM f32
// C(M,N) = A(M,K) @ B(K,N) [+bias] [relu] [+res]
// BMODE 0: B row-major (K,N).  BMODE 1: B is (H, K, 64) head-blocked (QKV).
// OMODE 0: C row-major.        OMODE 1: scatter to (b,h,s,e) layout.
template<int BMODE, int OMODE>
__global__ __launch_bounds__(256) void gemm_kernel(
    const float* __restrict__ A, const float* __restrict__ B,
    const float* __restrict__ bias, const float* __restrict__ res,
    float* __restrict__ C, int M, int N, int K, int relu)
{
    __shared__ float sA[16][132];   // [k][m], pitch 132 keeps float4 alignment
    __shared__ float sB[16][68];    // [k][n]
    int tid = threadIdx.x;
    int bm = blockIdx.x * 128, bn = blockIdx.y * 64;
    int tm = (tid >> 4) * 8, tn = (tid & 15) * 4;
    int am = tid >> 1, ak = (tid & 1) * 8;     // A staging: 8 floats (2x float4)
    int bk = tid >> 4, bnn = (tid & 15) * 4;   // B staging: 4 floats
    float acc[8][4] = {};
    for (int k0 = 0; k0 < K; k0 += 16) {
        float4 a0 = *(const float4*)(A + (size_t)(bm + am) * K + k0 + ak);
        float4 a1 = *(const float4*)(A + (size_t)(bm + am) * K + k0 + ak + 4);
        float4 bv;
        if (BMODE == 0) {
            bv = *(const float4*)(B + (size_t)(k0 + bk) * N + bn + bnn);
        } else {
            int col = bn + bnn; int hh = col >> 6; int e = col & 63;
            bv = *(const float4*)(B + ((size_t)hh * K + k0 + bk) * HS + e);
        }
        sA[ak+0][am]=a0.x; sA[ak+1][am]=a0.y; sA[ak+2][am]=a0.z; sA[ak+3][am]=a0.w;
        sA[ak+4][am]=a1.x; sA[ak+5][am]=a1.y; sA[ak+6][am]=a1.z; sA[ak+7][am]=a1.w;
        *(float4*)&sB[bk][bnn] = bv;
        __syncthreads();
        #pragma unroll
        for (int kk = 0; kk < 16; kk++) {
            float4 av0 = *(const float4*)&sA[kk][tm];
            float4 av1 = *(const float4*)&sA[kk][tm + 4];
            float4 bv2 = *(const float4*)&sB[kk][tn];
            float a_[8] = {av0.x,av0.y,av0.z,av0.w,av1.x,av1.y,av1.z,av1.w};
            float b_[4] = {bv2.x,bv2.y,bv2.z,bv2.w};
            #pragma unroll
            for (int i = 0; i < 8; i++)
                #pragma unroll
                for (int j = 0; j < 4; j++)
                    acc[i][j] = fmaf(a_[i], b_[j], acc[i][j]);
        }
        __syncthreads();
    }
    #pragma unroll
    for (int i = 0; i < 8; i++) {
        int row = bm + tm + i;
        #pragma unroll
        for (int j = 0; j < 4; j++) {
            int col = bn + tn + j;
            float v = acc[i][j];
            if (bias) v += bias[col];
            if (relu) v = fmaxf(v, 0.f);
            if (res)  v += res[(size_t)row * N + col];
            size_t oi;
            if (OMODE == 0) {
                oi = (size_t)row * N + col;
            } else {
                int bb = row >> 10, ss = row & 1023, hh = col >> 6, e = col & 63;
                oi = (((size_t)(bb * NHEAD + hh)) * SEQ + ss) * HS + e;
            }
            C[oi] = v;
        }
    }
}

// ---------------------------------------------------------------- attention
// one wave per (b, h, 64-row q-tile); online softmax over 16 K/V tiles.
// NOTE: reference scale = D_MODEL^-0.5, NOT HS^-0.5.
__global__ __launch_bounds__(64) void attn_kernel(
    const float* __restrict__ q, const float* __restrict__ k,
    const float* __restrict__ v, const int* __restrict__ mask,
    float* __restrict__ ao)
{
    __shared__ float Ks[64][65];   // pitch 65: conflict-free row writes
    __shared__ float Vs[64][65];
    int blk = blockIdx.x;
    int qt = blk & 15, bh = blk >> 4;
    int b = bh / NHEAD, hh = bh % NHEAD;
    int t = threadIdx.x;
    int sq = qt * 64 + t;
    const float scale = 0.036084391824351615f;  // 768^-0.5
    float qreg[64];
    const float* qrow = q + ((size_t)bh * SEQ + sq) * HS;
    #pragma unroll
    for (int e = 0; e < 64; e += 4) {
        float4 t4 = *(const float4*)(qrow + e);
        qreg[e] = t4.x * scale; qreg[e+1] = t4.y * scale;
        qreg[e+2] = t4.z * scale; qreg[e+3] = t4.w * scale;
    }
    float o[64];
    #pragma unroll
    for (int e = 0; e < 64; e++) o[e] = 0.f;
    float m = -1e30f, l = 0.f;
    const int* mrow = mask + (size_t)b * SEQ;
    for (int kt = 0; kt < 16; kt++) {
        const float* kb = k + ((size_t)bh * SEQ + kt * 64 + t) * HS;
        const float* vb = v + ((size_t)bh * SEQ + kt * 64 + t) * HS;
        #pragma unroll
        for (int e = 0; e < 64; e += 4) {
            float4 k4 = *(const float4*)(kb + e);
            Ks[t][e] = k4.x; Ks[t][e+1] = k4.y; Ks[t][e+2] = k4.z; Ks[t][e+3] = k4.w;
            float4 v4 = *(const float4*)(vb + e);
            Vs[t][e] = v4.x; Vs[t][e+1] = v4.y; Vs[t][e+2] = v4.z; Vs[t][e+3] = v4.w;
        }
        __syncthreads();
        for (int jc = 0; jc < 4; jc++) {
            float sc[16];
            float mloc = m;
            #pragma unroll
            for (int jj = 0; jj < 16; jj++) {
                const float* kr = &Ks[jc * 16 + jj][0];
                float d0 = 0, d1 = 0, d2 = 0, d3 = 0;
                #pragma unroll
                for (int e = 0; e < 64; e += 4) {
                    d0 = fmaf(qreg[e],   kr[e],   d0);
                    d1 = fmaf(qreg[e+1], kr[e+1], d1);
                    d2 = fmaf(qreg[e+2], kr[e+2], d2);
                    d3 = fmaf(qreg[e+3], kr[e+3], d3);
                }
                float d = (d0 + d1) + (d2 + d3);
                if (mrow[kt * 64 + jc * 16 + jj] == 0) d = -1e30f;
                sc[jj] = d;
                mloc = fmaxf(mloc, d);
            }
            float corr = __expf(m - mloc);
            m = mloc;
            l *= corr;
            #pragma unroll
            for (int e = 0; e < 64; e++) o[e] *= corr;
            #pragma unroll
            for (int jj = 0; jj < 16; jj++) {
                float p = __expf(sc[jj] - m);
                l += p;
                const float* vr = &Vs[jc * 16 + jj][0];
                #pragma unroll
                for (int e = 0; e < 64; e++) o[e] = fmaf(p, vr[e], o[e]);
            }
        }
        __syncthreads();
    }
    float inv = 1.f / l;
    float* orow = ao + ((size_t)(b * SEQ + sq)) * D_MODEL + hh * HS;
    #pragma unroll
    for (int e = 0; e < 64; e++) orow[e] = o[e] * inv;
}

// ---------------------------------------------------------------- tiny FC
__global__ void fc_kernel(const float* __restrict__ A, const float* __restrict__ W,
                          const float* __restrict__ bias, float* __restrict__ out,
                          int K, int N, int relu)
{
    int row = blockIdx.x;
    int col = blockIdx.y * blockDim.x + threadIdx.x;
    if (col >= N) return;
    const float* a = A + (size_t)row * K;
    float s = 0.f;
    for (int kk = 0; kk < K; kk++) s = fmaf(a[kk], W[(size_t)kk * N + col], s);
    s += bias[col];
    if (relu) s = fmaxf(s, 0.f);
    out[(size_t)row * N + col] = s;
}

// ---------------------------------------------------------------- launch
extern "C" void kernel_launch(void* const* d_in, const int* in_sizes, int n_in,
                              void* d_out, int out_size, void* d_ws, size_t ws_size,
                              hipStream_t stream)
{
    const int*   x     = (const int*)  d_in[0];
    const int*   amask = (const int*)  d_in[1];
    const float* tok   = (const float*)d_in[2];
    const float* pos   = (const float*)d_in[3];
    const float* Wq    = (const float*)d_in[4];
    const float* Wk    = (const float*)d_in[5];
    const float* Wv    = (const float*)d_in[6];
    const float* Wo    = (const float*)d_in[7];
    const float* bo    = (const float*)d_in[8];
    const float* ln1w  = (const float*)d_in[9];
    const float* ln1b  = (const float*)d_in[10];
    const float* ln2w  = (const float*)d_in[11];
    const float* ln2b  = (const float*)d_in[12];
    const float* W1    = (const float*)d_in[13];
    const float* b1    = (const float*)d_in[14];
    const float* W2    = (const float*)d_in[15];
    const float* b2    = (const float*)d_in[16];
    const float* lnfw  = (const float*)d_in[17];
    const float* lnfb  = (const float*)d_in[18];
    const float* cW1   = (const float*)d_in[19];
    const float* cb1   = (const float*)d_in[20];
    const float* cW2   = (const float*)d_in[21];
    const float* cb2   = (const float*)d_in[22];

    // workspace layout (floats): h, xn, q, k, v, ff, cls  (~227 MB total)
    float* ws = (float*)d_ws;
    const size_t MD = (size_t)MROWS * D_MODEL;
    float* h   = ws;
    float* xn  = ws + MD;          // also reused as attention output (b,s,d)
    float* qb  = ws + 2 * MD;
    float* kb  = ws + 3 * MD;
    float* vb  = ws + 4 * MD;
    float* ff  = ws + 5 * MD;
    float* cls = ws + 5 * MD + (size_t)MROWS * DFF;

    embed_kernel<<<MROWS, 256, 0, stream>>>(x, tok, pos, h);

    dim3 gD(MROWS / 128, D_MODEL / 64);   // N=768 GEMMs
    dim3 gF(MROWS / 128, DFF / 64);       // N=3072 GEMM
    for (int l = 0; l < NLAYER; l++) {
        ln_kernel<<<MROWS, 256, 0, stream>>>(h, ln1w + l * D_MODEL, ln1b + l * D_MODEL, xn, 1, 0);
        const size_t wqk = (size_t)l * NHEAD * D_MODEL * HS;   // = l*768*768
        gemm_kernel<1, 1><<<gD, 256, 0, stream>>>(xn, Wq + wqk, nullptr, nullptr, qb, MROWS, D_MODEL, D_MODEL, 0);
        gemm_kernel<1, 1><<<gD, 256, 0, stream>>>(xn, Wk + wqk, nullptr, nullptr, kb, MROWS, D_MODEL, D_MODEL, 0);
        gemm_kernel<1, 1><<<gD, 256, 0, stream>>>(xn, Wv + wqk, nullptr, nullptr, vb, MROWS, D_MODEL, D_MODEL, 0);
        attn_kernel<<<NB * NHEAD * (SEQ / 64), 64, 0, stream>>>(qb, kb, vb, amask, xn);
        gemm_kernel<0, 0><<<gD, 256, 0, stream>>>(xn, Wo + (size_t)l * D_MODEL * D_MODEL,
                                                  bo + l * D_MODEL, h, h, MROWS, D_MODEL, D_MODEL, 0);
        ln_kernel<<<MROWS, 256, 0, stream>>>(h, ln2w + l * D_MODEL, ln2b + l * D_MODEL, xn, 1, 0);
        gemm_kernel<0, 0><<<gF, 256, 0, stream>>>(xn, W1 + (size_t)l * D_MODEL * DFF,
                                                  b1 + l * DFF, nullptr, ff, MROWS, DFF, D_MODEL, 1);
        gemm_kernel<0, 0><<<gD, 256, 0, stream>>>(ff, W2 + (size_t)l * DFF * D_MODEL,
                                                  b2 + l * D_MODEL, h, h, MROWS, D_MODEL, DFF, 0);
    }
    // final LN on the 8 last-token rows only (equivalent to LN-then-slice)
    ln_kernel<<<NB, 256, 0, stream>>>(h, lnfw, lnfb, xn, SEQ, SEQ - 1);
    fc_kernel<<<dim3(NB, DFF / 256), 256, 0, stream>>>(xn, cW1, cb1, cls, D_MODEL, DFF, 1);
    fc_kernel<<<dim3(NB, 1), 64, 0, stream>>>(cls, cW2, cb2, (float*)d_out, DFF, NCLS, 0);
}

// Round 2
// 7419.588 us; speedup vs baseline: 2.2639x; 2.2639x over previous
//
#include <hip/hip_runtime.h>
#include <hip/hip_bf16.h>

#define D_MODEL 768
#define SEQ     1024
#define NB      8
#define NHEAD   12
#define HS      64
#define NLAYER  4
#define DFF     3072
#define NCLS    16
#define MROWS   (NB*SEQ)   // 8192

typedef float f32x4  __attribute__((ext_vector_type(4)));
typedef short bf16x8 __attribute__((ext_vector_type(8)));

__device__ __forceinline__ float bf_lo(unsigned int u){ return __uint_as_float(u << 16); }
__device__ __forceinline__ float bf_hi(unsigned int u){ return __uint_as_float(u & 0xffff0000u); }

// ---------------------------------------------------------------- embedding
__global__ __launch_bounds__(256) void embed_kernel(
    const int* __restrict__ x, const float* __restrict__ tok,
    const float* __restrict__ pos, float* __restrict__ h)
{
    int row = blockIdx.x;
    int s   = row & (SEQ - 1);
    int t   = threadIdx.x;
    int id  = x[row];
    const float* te = tok + (size_t)id * D_MODEL;
    const float* pe = pos + (size_t)s  * D_MODEL;
    float* hr = h + (size_t)row * D_MODEL;
    for (int d = t; d < D_MODEL; d += 256) hr[d] = te[d] + pe[d];
}

// ---------------------------------------------------------------- layernorm
// one block per output row; input row = r*row_stride + row_offset
template<int BF16OUT>
__global__ __launch_bounds__(256) void ln_kernel(
    const float* __restrict__ in, const float* __restrict__ w,
    const float* __restrict__ b, void* __restrict__ outv,
    int row_stride, int row_offset)
{
    __shared__ float red[256];
    int r = blockIdx.x;
    const float* xr = in + (size_t)(r * row_stride + row_offset) * D_MODEL;
    int t = threadIdx.x;
    float v0 = xr[t], v1 = xr[t + 256], v2 = xr[t + 512];
    red[t] = v0 + v1 + v2; __syncthreads();
    for (int off = 128; off; off >>= 1) { if (t < off) red[t] += red[t + off]; __syncthreads(); }
    float mu = red[0] * (1.f / D_MODEL);
    __syncthreads();
    float d0 = v0 - mu, d1 = v1 - mu, d2 = v2 - mu;
    red[t] = d0*d0 + d1*d1 + d2*d2; __syncthreads();
    for (int off = 128; off; off >>= 1) { if (t < off) red[t] += red[t + off]; __syncthreads(); }
    float rstd = rsqrtf(red[0] * (1.f / D_MODEL) + 1e-5f);
    float y0 = d0 * rstd * w[t]       + b[t];
    float y1 = d1 * rstd * w[t + 256] + b[t + 256];
    float y2 = d2 * rstd * w[t + 512] + b[t + 512];
    if (BF16OUT) {
        __hip_bfloat16* yr = (__hip_bfloat16*)outv + (size_t)r * D_MODEL;
        yr[t] = __float2bfloat16(y0); yr[t+256] = __float2bfloat16(y1); yr[t+512] = __float2bfloat16(y2);
    } else {
        float* yr = (float*)outv + (size_t)r * D_MODEL;
        yr[t] = y0; yr[t+256] = y1; yr[t+512] = y2;
    }
}

// --------------------------------------------- weight convert+transpose to bf16
// out BT[N][K] (row-major, bf16) from f32 input.
// MODE 0: in[k*N + n]   MODE 1 (QKV head-blocked): in[((n>>6)*K + k)*64 + (n&63)]
template<int MODE>
__global__ __launch_bounds__(256) void convw_kernel(
    const float* __restrict__ W, __hip_bfloat16* __restrict__ BT,
    int K, int N, size_t in_stride, size_t out_stride)
{
    __shared__ __hip_bfloat16 sT[64][72];
    W  += (size_t)blockIdx.z * in_stride;
    BT += (size_t)blockIdx.z * out_stride;
    int k0 = blockIdx.x * 64, n0 = blockIdx.y * 64;
    int t = threadIdx.x;
    int kl = t >> 4, nl4 = (t & 15) * 4;
    #pragma unroll
    for (int i = 0; i < 4; i++) {
        int k = k0 + kl + i * 16;
        int n = n0 + nl4;
        const float* src = (MODE == 0) ? (W + (size_t)k * N + n)
                                       : (W + ((size_t)(n >> 6) * K + k) * 64 + (n & 63));
        float4 v = *(const float4*)src;
        sT[nl4 + 0][kl + i*16] = __float2bfloat16(v.x);
        sT[nl4 + 1][kl + i*16] = __float2bfloat16(v.y);
        sT[nl4 + 2][kl + i*16] = __float2bfloat16(v.z);
        sT[nl4 + 3][kl + i*16] = __float2bfloat16(v.w);
    }
    __syncthreads();
    int nl = t >> 2, seg = (t & 3) * 16;
    uint4* dst = (uint4*)(BT + (size_t)(n0 + nl) * K + k0 + seg);
    dst[0] = *(uint4*)&sT[nl][seg];
    dst[1] = *(uint4*)&sT[nl][seg + 8];
}

// ---------------------------------------------------------------- bf16 MFMA GEMM
// C(M,N) = A(M,K) @ B(K,N), A bf16 row-major, BT = B^T bf16 (N rows of K).
// BN fixed 128. BM template (64 or 128). 256 threads = 4 waves in 2x2 wave grid.
// OMODE 0: C f32 row-major (+bias,+res).  1: bf16 scatter to (b,h,s,e) (QKV).
// OMODE 2: C bf16 row-major (+bias, relu flag).
// MFMA 16x16x32 bf16 layouts (verified m89/m91/m120):
//   A-frag: lane holds A[m=lane&15][k=quad*8+j]; B-frag: BT row (col n=lane&15);
//   C/D: row=quad*4+reg, col=lane&15.
template<int BM, int OMODE>
__global__ __launch_bounds__(256, 3) void gemm_bf16(
    const __hip_bfloat16* __restrict__ A, const __hip_bfloat16* __restrict__ BT,
    const float* __restrict__ bias, const float* __restrict__ res,
    void* __restrict__ Cv, int M, int N, int K, int relu)
{
    constexpr int MI = BM / 32;           // MFMA row-tiles per wave
    constexpr int ASTEPS = BM / 64;       // staging iterations for A
    __shared__ short sA[BM * 40];         // [m][k] pitch 40 bf16 (2-way bank alias = free)
    __shared__ short sB[128 * 40];        // [n][k] pitch 40
    int t = threadIdx.x;
    int wave = t >> 6, l16 = t & 15, quad = (t >> 4) & 3;
    int wm = wave >> 1, wn = wave & 1;
    int bm = blockIdx.x * BM, bn = blockIdx.y * 128;
    const f32x4 zf = {0.f, 0.f, 0.f, 0.f};
    f32x4 acc[MI][4];
    #pragma unroll
    for (int mi = 0; mi < MI; mi++)
        #pragma unroll
        for (int ni = 0; ni < 4; ni++) acc[mi][ni] = zf;

    for (int k0 = 0; k0 < K; k0 += 32) {
        uint4 aL[ASTEPS], bL[2];
        #pragma unroll
        for (int i = 0; i < ASTEPS; i++) {
            int idx = t + i * 256; int row = idx >> 2, seg = idx & 3;
            aL[i] = *(const uint4*)(A + (size_t)(bm + row) * K + k0 + seg * 8);
        }
        #pragma unroll
        for (int i = 0; i < 2; i++) {
            int idx = t + i * 256; int row = idx >> 2, seg = idx & 3;
            bL[i] = *(const uint4*)(BT + (size_t)(bn + row) * K + k0 + seg * 8);
        }
        __syncthreads();
        #pragma unroll
        for (int i = 0; i < ASTEPS; i++) {
            int idx = t + i * 256; int row = idx >> 2, seg = idx & 3;
            *(uint4*)&sA[row * 40 + seg * 8] = aL[i];
        }
        #pragma unroll
        for (int i = 0; i < 2; i++) {
            int idx = t + i * 256; int row = idx >> 2, seg = idx & 3;
            *(uint4*)&sB[row * 40 + seg * 8] = bL[i];
        }
        __syncthreads();
        bf16x8 aF[MI], bF[4];
        #pragma unroll
        for (int mi = 0; mi < MI; mi++)
            aF[mi] = *(bf16x8*)&sA[(wm * (BM/2) + mi * 16 + l16) * 40 + quad * 8];
        #pragma unroll
        for (int ni = 0; ni < 4; ni++)
            bF[ni] = *(bf16x8*)&sB[(wn * 64 + ni * 16 + l16) * 40 + quad * 8];
        #pragma unroll
        for (int ni = 0; ni < 4; ni++)
            #pragma unroll
            for (int mi = 0; mi < MI; mi++)
                acc[mi][ni] = __builtin_amdgcn_mfma_f32_16x16x32_bf16(aF[mi], bF[ni], acc[mi][ni], 0, 0, 0);
        __syncthreads();
    }
    #pragma unroll
    for (int mi = 0; mi < MI; mi++) {
        #pragma unroll
        for (int ni = 0; ni < 4; ni++) {
            int row0 = bm + wm * (BM/2) + mi * 16 + quad * 4;
            int col  = bn + wn * 64 + ni * 16 + l16;
            #pragma unroll
            for (int r = 0; r < 4; r++) {
                int row = row0 + r;
                float v = acc[mi][ni][r];
                if (OMODE != 1 && bias) v += bias[col];
                if (relu) v = fmaxf(v, 0.f);
                if (OMODE == 0) {
                    float* C = (float*)Cv;
                    if (res) v += res[(size_t)row * N + col];
                    C[(size_t)row * N + col] = v;
                } else if (OMODE == 1) {
                    int bb = row >> 10, ss = row & 1023, hh = col >> 6, e = col & 63;
                    ((__hip_bfloat16*)Cv)[(((size_t)(bb * NHEAD + hh)) * SEQ + ss) * HS + e] = __float2bfloat16(v);
                } else {
                    ((__hip_bfloat16*)Cv)[(size_t)row * N + col] = __float2bfloat16(v);
                }
            }
        }
    }
    (void)M;
}

// ---------------------------------------------------------------- attention
// one wave per (b, h, 64-row q-tile); online softmax; 32-row bf16 K/V tiles
// staged to f32 LDS (17 KB -> 6 resident waves/CU vs 4 at 33 KB).
// NOTE: reference scale = D_MODEL^-0.5, NOT HS^-0.5.
__global__ __launch_bounds__(64) void attn_kernel(
    const __hip_bfloat16* __restrict__ q, const __hip_bfloat16* __restrict__ k,
    const __hip_bfloat16* __restrict__ v, const int* __restrict__ mask,
    __hip_bfloat16* __restrict__ ao)
{
    __shared__ float Ks[32][68];
    __shared__ float Vs[32][68];
    int blk = blockIdx.x;
    int qt = blk & 15, bh = blk >> 4;
    int b = bh / NHEAD, hh = bh % NHEAD;
    int t = threadIdx.x;
    int sq = qt * 64 + t;
    const float scale = 0.036084391824351615f;  // 768^-0.5
    float qreg[64];
    const __hip_bfloat16* qrow = q + ((size_t)bh * SEQ + sq) * HS;
    #pragma unroll
    for (int i = 0; i < 8; i++) {
        uint4 u = ((const uint4*)qrow)[i];
        qreg[i*8+0] = bf_lo(u.x) * scale; qreg[i*8+1] = bf_hi(u.x) * scale;
        qreg[i*8+2] = bf_lo(u.y) * scale; qreg[i*8+3] = bf_hi(u.y) * scale;
        qreg[i*8+4] = bf_lo(u.z) * scale; qreg[i*8+5] = bf_hi(u.z) * scale;
        qreg[i*8+6] = bf_lo(u.w) * scale; qreg[i*8+7] = bf_hi(u.w) * scale;
    }
    float o[64];
    #pragma unroll
    for (int e = 0; e < 64; e++) o[e] = 0.f;
    float m = -1e30f, l = 0.f;
    const int* mrow = mask + (size_t)b * SEQ;
    int srow = t >> 1, half = (t & 1) * 32;
    for (int kt = 0; kt < 32; kt++) {
        const __hip_bfloat16* kbp = k + ((size_t)bh * SEQ + kt * 32 + srow) * HS + half;
        const __hip_bfloat16* vbp = v + ((size_t)bh * SEQ + kt * 32 + srow) * HS + half;
        #pragma unroll
        for (int i = 0; i < 4; i++) {
            uint4 u = ((const uint4*)kbp)[i];
            float* d = &Ks[srow][half + i * 8];
            d[0]=bf_lo(u.x); d[1]=bf_hi(u.x); d[2]=bf_lo(u.y); d[3]=bf_hi(u.y);
            d[4]=bf_lo(u.z); d[5]=bf_hi(u.z); d[6]=bf_lo(u.w); d[7]=bf_hi(u.w);
            uint4 w = ((const uint4*)vbp)[i];
            float* e2 = &Vs[srow][half + i * 8];
            e2[0]=bf_lo(w.x); e2[1]=bf_hi(w.x); e2[2]=bf_lo(w.y); e2[3]=bf_hi(w.y);
            e2[4]=bf_lo(w.z); e2[5]=bf_hi(w.z); e2[6]=bf_lo(w.w); e2[7]=bf_hi(w.w);
        }
        __syncthreads();
        for (int jc = 0; jc < 2; jc++) {
            float sc[16];
            float mloc = m;
            #pragma unroll
            for (int jj = 0; jj < 16; jj++) {
                const float* kr = &Ks[jc * 16 + jj][0];
                float d0 = 0, d1 = 0, d2 = 0, d3 = 0;
                #pragma unroll
                for (int e = 0; e < 64; e += 4) {
                    d0 = fmaf(qreg[e],   kr[e],   d0);
                    d1 = fmaf(qreg[e+1], kr[e+1], d1);
                    d2 = fmaf(qreg[e+2], kr[e+2], d2);
                    d3 = fmaf(qreg[e+3], kr[e+3], d3);
                }
                float d = (d0 + d1) + (d2 + d3);
                if (mrow[kt * 32 + jc * 16 + jj] == 0) d = -1e30f;
                sc[jj] = d;
                mloc = fmaxf(mloc, d);
            }
            float corr = __expf(m - mloc);
            m = mloc;
            l *= corr;
            #pragma unroll
            for (int e = 0; e < 64; e++) o[e] *= corr;
            #pragma unroll
            for (int jj = 0; jj < 16; jj++) {
                float p = __expf(sc[jj] - m);
                l += p;
                const float* vr = &Vs[jc * 16 + jj][0];
                #pragma unroll
                for (int e = 0; e < 64; e++) o[e] = fmaf(p, vr[e], o[e]);
            }
        }
        __syncthreads();
    }
    float inv = 1.f / l;
    __hip_bfloat16* orow = ao + ((size_t)(b * SEQ + sq)) * D_MODEL + hh * HS;
    #pragma unroll
    for (int e = 0; e < 64; e++) orow[e] = __float2bfloat16(o[e] * inv);
}

// ---------------------------------------------------------------- tiny FC (f32)
__global__ void fc_kernel(const float* __restrict__ A, const float* __restrict__ W,
                          const float* __restrict__ bias, float* __restrict__ out,
                          int K, int N, int relu)
{
    int row = blockIdx.x;
    int col = blockIdx.y * blockDim.x + threadIdx.x;
    if (col >= N) return;
    const float* a = A + (size_t)row * K;
    float s = 0.f;
    for (int kk = 0; kk < K; kk++) s = fmaf(a[kk], W[(size_t)kk * N + col], s);
    s += bias[col];
    if (relu) s = fmaxf(s, 0.f);
    out[(size_t)row * N + col] = s;
}

// ---------------------------------------------------------------- launch
extern "C" void kernel_launch(void* const* d_in, const int* in_sizes, int n_in,
                              void* d_out, int out_size, void* d_ws, size_t ws_size,
                              hipStream_t stream)
{
    const int*   x     = (const int*)  d_in[0];
    const int*   amask = (const int*)  d_in[1];
    const float* tok   = (const float*)d_in[2];
    const float* pos   = (const float*)d_in[3];
    const float* Wq    = (const float*)d_in[4];
    const float* Wk    = (const float*)d_in[5];
    const float* Wv    = (const float*)d_in[6];
    const float* Wo    = (const float*)d_in[7];
    const float* bo    = (const float*)d_in[8];
    const float* ln1w  = (const float*)d_in[9];
    const float* ln1b  = (const float*)d_in[10];
    const float* ln2w  = (const float*)d_in[11];
    const float* ln2b  = (const float*)d_in[12];
    const float* W1    = (const float*)d_in[13];
    const float* b1    = (const float*)d_in[14];
    const float* W2    = (const float*)d_in[15];
    const float* b2    = (const float*)d_in[16];
    const float* lnfw  = (const float*)d_in[17];
    const float* lnfb  = (const float*)d_in[18];
    const float* cW1   = (const float*)d_in[19];
    const float* cb1   = (const float*)d_in[20];
    const float* cW2   = (const float*)d_in[21];
    const float* cb2   = (const float*)d_in[22];

    // ---- workspace layout (bytes; all chunks 16B-aligned) ~183 MB total
    char* base = (char*)d_ws;
    float* h = (float*)base;                         base += (size_t)MROWS * D_MODEL * 4;   // 25.2 MB
    __hip_bfloat16* xn = (__hip_bfloat16*)base;      base += (size_t)MROWS * D_MODEL * 2;   // LN out / attn out
    __hip_bfloat16* qb = (__hip_bfloat16*)base;      base += (size_t)MROWS * D_MODEL * 2;
    __hip_bfloat16* kb = (__hip_bfloat16*)base;      base += (size_t)MROWS * D_MODEL * 2;
    __hip_bfloat16* vb = (__hip_bfloat16*)base;      base += (size_t)MROWS * D_MODEL * 2;
    __hip_bfloat16* ff = (__hip_bfloat16*)base;      base += (size_t)MROWS * DFF * 2;       // 50.3 MB
    float* lnf = (float*)base;                       base += (size_t)NB * D_MODEL * 4;
    float* cls = (float*)base;                       base += (size_t)NB * DFF * 4;
    __hip_bfloat16* wTq = (__hip_bfloat16*)base;     base += (size_t)NLAYER * D_MODEL * D_MODEL * 2;
    __hip_bfloat16* wTk = (__hip_bfloat16*)base;     base += (size_t)NLAYER * D_MODEL * D_MODEL * 2;
    __hip_bfloat16* wTv = (__hip_bfloat16*)base;     base += (size_t)NLAYER * D_MODEL * D_MODEL * 2;
    __hip_bfloat16* wTo = (__hip_bfloat16*)base;     base += (size_t)NLAYER * D_MODEL * D_MODEL * 2;
    __hip_bfloat16* wT1 = (__hip_bfloat16*)base;     base += (size_t)NLAYER * D_MODEL * DFF * 2;
    __hip_bfloat16* wT2 = (__hip_bfloat16*)base;     base += (size_t)NLAYER * DFF * D_MODEL * 2;

    const size_t SQW = (size_t)D_MODEL * D_MODEL;    // 589824
    const size_t SFF = (size_t)D_MODEL * DFF;        // 2359296

    // ---- weight convert + transpose to bf16 (once per launch, idempotent)
    convw_kernel<1><<<dim3(12,12,4), 256, 0, stream>>>(Wq, wTq, D_MODEL, D_MODEL, SQW, SQW);
    convw_kernel<1><<<dim3(12,12,4), 256, 0, stream>>>(Wk, wTk, D_MODEL, D_MODEL, SQW, SQW);
    convw_kernel<1><<<dim3(12,12,4), 256, 0, stream>>>(Wv, wTv, D_MODEL, D_MODEL, SQW, SQW);
    convw_kernel<0><<<dim3(12,12,4), 256, 0, stream>>>(Wo, wTo, D_MODEL, D_MODEL, SQW, SQW);
    convw_kernel<0><<<dim3(12,48,4), 256, 0, stream>>>(W1, wT1, D_MODEL, DFF, SFF, SFF);
    convw_kernel<0><<<dim3(48,12,4), 256, 0, stream>>>(W2, wT2, DFF, D_MODEL, SFF, SFF);

    embed_kernel<<<MROWS, 256, 0, stream>>>(x, tok, pos, h);

    dim3 gD(MROWS / 64, D_MODEL / 128);   // BM=64 grid for N=768 GEMMs: (128, 6)
    dim3 gF(MROWS / 128, DFF / 128);      // BM=128 grid for W1: (64, 24)
    for (int l = 0; l < NLAYER; l++) {
        ln_kernel<1><<<MROWS, 256, 0, stream>>>(h, ln1w + l * D_MODEL, ln1b + l * D_MODEL, xn, 1, 0);
        gemm_bf16<64,1><<<gD, 256, 0, stream>>>(xn, wTq + l * SQW, nullptr, nullptr, qb, MROWS, D_MODEL, D_MODEL, 0);
        gemm_bf16<64,1><<<gD, 256, 0, stream>>>(xn, wTk + l * SQW, nullptr, nullptr, kb, MROWS, D_MODEL, D_MODEL, 0);
        gemm_bf16<64,1><<<gD, 256, 0, stream>>>(xn, wTv + l * SQW, nullptr, nullptr, vb, MROWS, D_MODEL, D_MODEL, 0);
        attn_kernel<<<NB * NHEAD * (SEQ / 64), 64, 0, stream>>>(qb, kb, vb, amask, xn);
        gemm_bf16<64,0><<<gD, 256, 0, stream>>>(xn, wTo + l * SQW, bo + l * D_MODEL, h, h, MROWS, D_MODEL, D_MODEL, 0);
        ln_kernel<1><<<MROWS, 256, 0, stream>>>(h, ln2w + l * D_MODEL, ln2b + l * D_MODEL, xn, 1, 0);
        gemm_bf16<128,2><<<gF, 256, 0, stream>>>(xn, wT1 + l * SFF, b1 + l * DFF, nullptr, ff, MROWS, DFF, D_MODEL, 1);
        gemm_bf16<64,0><<<gD, 256, 0, stream>>>(ff, wT2 + l * SFF, b2 + l * D_MODEL, h, h, MROWS, D_MODEL, DFF, 0);
    }
    // final LN on the 8 last-token rows only (equivalent to LN-then-slice)
    ln_kernel<0><<<NB, 256, 0, stream>>>(h, lnfw, lnfb, lnf, SEQ, SEQ - 1);
    fc_kernel<<<dim3(NB, DFF / 256), 256, 0, stream>>>(lnf, cW1, cb1, cls, D_MODEL, DFF, 1);
    fc_kernel<<<dim3(NB, 1), 64, 0, stream>>>(cls, cW2, cb2, (float*)d_out, DFF, NCLS, 0);
}

// Round 3
// 4497.121 us; speedup vs baseline: 3.7351x; 1.6499x over previous
//
#include <hip/hip_runtime.h>
#include <hip/hip_bf16.h>

#define D_MODEL 768
#define SEQ     1024
#define NB      8
#define NHEAD   12
#define HS      64
#define NLAYER  4
#define DFF     3072
#define NCLS    16
#define MROWS   (NB*SEQ)   // 8192

typedef float f32x4  __attribute__((ext_vector_type(4)));
typedef short bf16x8 __attribute__((ext_vector_type(8)));

__device__ __forceinline__ short f2bf_s(float x) {
    __hip_bfloat16 h = __float2bfloat16(x);
    union { __hip_bfloat16 h; short s; } u; u.h = h; return u.s;
}

// ---------------------------------------------------------------- embedding
__global__ __launch_bounds__(256) void embed_kernel(
    const int* __restrict__ x, const float* __restrict__ tok,
    const float* __restrict__ pos, float* __restrict__ h)
{
    int row = blockIdx.x;
    int s   = row & (SEQ - 1);
    int t   = threadIdx.x;
    int id  = x[row];
    const float* te = tok + (size_t)id * D_MODEL;
    const float* pe = pos + (size_t)s  * D_MODEL;
    float* hr = h + (size_t)row * D_MODEL;
    for (int d = t; d < D_MODEL; d += 256) hr[d] = te[d] + pe[d];
}

// ---------------------------------------------------------------- layernorm
template<int BF16OUT>
__global__ __launch_bounds__(256) void ln_kernel(
    const float* __restrict__ in, const float* __restrict__ w,
    const float* __restrict__ b, void* __restrict__ outv,
    int row_stride, int row_offset)
{
    __shared__ float red[256];
    int r = blockIdx.x;
    const float* xr = in + (size_t)(r * row_stride + row_offset) * D_MODEL;
    int t = threadIdx.x;
    float v0 = xr[t], v1 = xr[t + 256], v2 = xr[t + 512];
    red[t] = v0 + v1 + v2; __syncthreads();
    for (int off = 128; off; off >>= 1) { if (t < off) red[t] += red[t + off]; __syncthreads(); }
    float mu = red[0] * (1.f / D_MODEL);
    __syncthreads();
    float d0 = v0 - mu, d1 = v1 - mu, d2 = v2 - mu;
    red[t] = d0*d0 + d1*d1 + d2*d2; __syncthreads();
    for (int off = 128; off; off >>= 1) { if (t < off) red[t] += red[t + off]; __syncthreads(); }
    float rstd = rsqrtf(red[0] * (1.f / D_MODEL) + 1e-5f);
    float y0 = d0 * rstd * w[t]       + b[t];
    float y1 = d1 * rstd * w[t + 256] + b[t + 256];
    float y2 = d2 * rstd * w[t + 512] + b[t + 512];
    if (BF16OUT) {
        __hip_bfloat16* yr = (__hip_bfloat16*)outv + (size_t)r * D_MODEL;
        yr[t] = __float2bfloat16(y0); yr[t+256] = __float2bfloat16(y1); yr[t+512] = __float2bfloat16(y2);
    } else {
        float* yr = (float*)outv + (size_t)r * D_MODEL;
        yr[t] = y0; yr[t+256] = y1; yr[t+512] = y2;
    }
}

// --------------------------------------------- weight convert+transpose to bf16
template<int MODE>
__global__ __launch_bounds__(256) void convw_kernel(
    const float* __restrict__ W, __hip_bfloat16* __restrict__ BT,
    int K, int N, size_t in_stride, size_t out_stride)
{
    __shared__ __hip_bfloat16 sT[64][72];
    W  += (size_t)blockIdx.z * in_stride;
    BT += (size_t)blockIdx.z * out_stride;
    int k0 = blockIdx.x * 64, n0 = blockIdx.y * 64;
    int t = threadIdx.x;
    int kl = t >> 4, nl4 = (t & 15) * 4;
    #pragma unroll
    for (int i = 0; i < 4; i++) {
        int k = k0 + kl + i * 16;
        int n = n0 + nl4;
        const float* src = (MODE == 0) ? (W + (size_t)k * N + n)
                                       : (W + ((size_t)(n >> 6) * K + k) * 64 + (n & 63));
        float4 v = *(const float4*)src;
        sT[nl4 + 0][kl + i*16] = __float2bfloat16(v.x);
        sT[nl4 + 1][kl + i*16] = __float2bfloat16(v.y);
        sT[nl4 + 2][kl + i*16] = __float2bfloat16(v.z);
        sT[nl4 + 3][kl + i*16] = __float2bfloat16(v.w);
    }
    __syncthreads();
    int nl = t >> 2, seg = (t & 3) * 16;
    uint4* dst = (uint4*)(BT + (size_t)(n0 + nl) * K + k0 + seg);
    dst[0] = *(uint4*)&sT[nl][seg];
    dst[1] = *(uint4*)&sT[nl][seg + 8];
}

// ---------------------------------------------------------------- bf16 MFMA GEMM
template<int BM, int OMODE>
__global__ __launch_bounds__(256, 3) void gemm_bf16(
    const __hip_bfloat16* __restrict__ A, const __hip_bfloat16* __restrict__ BT,
    const float* __restrict__ bias, const float* __restrict__ res,
    void* __restrict__ Cv, int M, int N, int K, int relu)
{
    constexpr int MI = BM / 32;
    constexpr int ASTEPS = BM / 64;
    __shared__ short sA[BM * 40];
    __shared__ short sB[128 * 40];
    int t = threadIdx.x;
    int wave = t >> 6, l16 = t & 15, quad = (t >> 4) & 3;
    int wm = wave >> 1, wn = wave & 1;
    int bm = blockIdx.x * BM, bn = blockIdx.y * 128;
    const f32x4 zf = {0.f, 0.f, 0.f, 0.f};
    f32x4 acc[MI][4];
    #pragma unroll
    for (int mi = 0; mi < MI; mi++)
        #pragma unroll
        for (int ni = 0; ni < 4; ni++) acc[mi][ni] = zf;

    for (int k0 = 0; k0 < K; k0 += 32) {
        uint4 aL[ASTEPS], bL[2];
        #pragma unroll
        for (int i = 0; i < ASTEPS; i++) {
            int idx = t + i * 256; int row = idx >> 2, seg = idx & 3;
            aL[i] = *(const uint4*)(A + (size_t)(bm + row) * K + k0 + seg * 8);
        }
        #pragma unroll
        for (int i = 0; i < 2; i++) {
            int idx = t + i * 256; int row = idx >> 2, seg = idx & 3;
            bL[i] = *(const uint4*)(BT + (size_t)(bn + row) * K + k0 + seg * 8);
        }
        __syncthreads();
        #pragma unroll
        for (int i = 0; i < ASTEPS; i++) {
            int idx = t + i * 256; int row = idx >> 2, seg = idx & 3;
            *(uint4*)&sA[row * 40 + seg * 8] = aL[i];
        }
        #pragma unroll
        for (int i = 0; i < 2; i++) {
            int idx = t + i * 256; int row = idx >> 2, seg = idx & 3;
            *(uint4*)&sB[row * 40 + seg * 8] = bL[i];
        }
        __syncthreads();
        bf16x8 aF[MI], bF[4];
        #pragma unroll
        for (int mi = 0; mi < MI; mi++)
            aF[mi] = *(bf16x8*)&sA[(wm * (BM/2) + mi * 16 + l16) * 40 + quad * 8];
        #pragma unroll
        for (int ni = 0; ni < 4; ni++)
            bF[ni] = *(bf16x8*)&sB[(wn * 64 + ni * 16 + l16) * 40 + quad * 8];
        #pragma unroll
        for (int ni = 0; ni < 4; ni++)
            #pragma unroll
            for (int mi = 0; mi < MI; mi++)
                acc[mi][ni] = __builtin_amdgcn_mfma_f32_16x16x32_bf16(aF[mi], bF[ni], acc[mi][ni], 0, 0, 0);
        __syncthreads();
    }
    #pragma unroll
    for (int mi = 0; mi < MI; mi++) {
        #pragma unroll
        for (int ni = 0; ni < 4; ni++) {
            int row0 = bm + wm * (BM/2) + mi * 16 + quad * 4;
            int col  = bn + wn * 64 + ni * 16 + l16;
            #pragma unroll
            for (int r = 0; r < 4; r++) {
                int row = row0 + r;
                float v = acc[mi][ni][r];
                if (OMODE != 1 && bias) v += bias[col];
                if (relu) v = fmaxf(v, 0.f);
                if (OMODE == 0) {
                    float* C = (float*)Cv;
                    if (res) v += res[(size_t)row * N + col];
                    C[(size_t)row * N + col] = v;
                } else if (OMODE == 1) {
                    int bb = row >> 10, ss = row & 1023, hh = col >> 6, e = col & 63;
                    ((__hip_bfloat16*)Cv)[(((size_t)(bb * NHEAD + hh)) * SEQ + ss) * HS + e] = __float2bfloat16(v);
                } else {
                    ((__hip_bfloat16*)Cv)[(size_t)row * N + col] = __float2bfloat16(v);
                }
            }
        }
    }
    (void)M;
}

// ---------------------------------------------------------------- MFMA flash attention
// Block = 4 waves = 256 queries of one (b,h); wave owns 64 queries.
// Per 64-key chunk: stage K(key,dim) and VT(dim,key) in XOR-swizzled LDS;
// QK^T via mfma(A=Q,B=K-rows) -> C-layout scores (row=quad*4+reg=query, col=l16=key);
// online softmax (16-lane butterflies); P -> per-wave LDS -> A-frags; PV via
// mfma(A=P, B=VT-rows) accumulating O in C-layout (rows align with score rows).
// LDS addr (bf16 units): row*64 + ((seg8 ^ (row&7))*8 + in-seg)  [seg8 = dim/8]
// NOTE: reference scale = D_MODEL^-0.5.
__global__ __launch_bounds__(256, 1) void attn_mfma_kernel(
    const __hip_bfloat16* __restrict__ q, const __hip_bfloat16* __restrict__ k,
    const __hip_bfloat16* __restrict__ v, const int* __restrict__ mask,
    __hip_bfloat16* __restrict__ ao)
{
    __shared__ short sK[64 * 64];
    __shared__ short sVT[64 * 64];
    __shared__ short sP[4][64 * 64];
    __shared__ float msk[SEQ];
    int blk = blockIdx.x;
    int qt = blk & 3, bh = blk >> 2;
    int b = bh / NHEAD, hh = bh % NHEAD;
    int t = threadIdx.x, wave = t >> 6, lane = t & 63;
    int l16 = lane & 15, quad = lane >> 4;
    const float scale = 0.036084391824351615f;  // 768^-0.5
    const f32x4 zf = {0.f, 0.f, 0.f, 0.f};

    #pragma unroll
    for (int i = 0; i < 4; i++) {
        int idx = t + i * 256;
        msk[idx] = mask[b * SEQ + idx] ? 0.f : -1e30f;
    }

    // Q fragments: qf[mi][s] -> lane holds Q[qb0+mi*16+l16][s*32+quad*8 .. +7]
    int qb0 = qt * 256 + wave * 64;
    const __hip_bfloat16* qbase = q + ((size_t)bh * SEQ + qb0) * HS;
    bf16x8 qf[4][2];
    #pragma unroll
    for (int mi = 0; mi < 4; mi++)
        #pragma unroll
        for (int s = 0; s < 2; s++)
            qf[mi][s] = *(const bf16x8*)(qbase + (mi * 16 + l16) * HS + s * 32 + quad * 8);

    f32x4 accO[4][4];
    float m_st[4][4], l_st[4][4];
    #pragma unroll
    for (int mi = 0; mi < 4; mi++) {
        #pragma unroll
        for (int nt = 0; nt < 4; nt++) accO[mi][nt] = zf;
        #pragma unroll
        for (int r = 0; r < 4; r++) { m_st[mi][r] = -1e30f; l_st[mi][r] = 0.f; }
    }

    short* myP = &sP[wave][0];
    for (int kc = 0; kc < 16; kc++) {
        // ---- stage K and VT (transposed) for this 64-key chunk
        const __hip_bfloat16* kg = k + ((size_t)bh * SEQ + kc * 64) * HS;
        const __hip_bfloat16* vg = v + ((size_t)bh * SEQ + kc * 64) * HS;
        #pragma unroll
        for (int i = 0; i < 2; i++) {
            int idx = t + i * 256;
            int key = idx >> 3, seg = idx & 7;
            uint4 kv = *(const uint4*)(kg + key * HS + seg * 8);
            *(uint4*)&sK[key * 64 + ((seg ^ (key & 7)) * 8)] = kv;
            union { uint4 u; short s[8]; } vu;
            vu.u = *(const uint4*)(vg + key * HS + seg * 8);
            #pragma unroll
            for (int jj = 0; jj < 8; jj++) {
                int dim = seg * 8 + jj;
                sVT[dim * 64 + (((key >> 3) ^ jj) * 8) + (key & 7)] = vu.s[jj];
            }
        }
        __syncthreads();

        // ---- QK^T
        bf16x8 kf[4][2];
        #pragma unroll
        for (int nt = 0; nt < 4; nt++)
            #pragma unroll
            for (int s = 0; s < 2; s++)
                kf[nt][s] = *(bf16x8*)&sK[(nt * 16 + l16) * 64 + (((s * 4 + quad) ^ (l16 & 7)) * 8)];
        f32x4 sc[4][4];
        #pragma unroll
        for (int mi = 0; mi < 4; mi++)
            #pragma unroll
            for (int nt = 0; nt < 4; nt++) {
                f32x4 c = __builtin_amdgcn_mfma_f32_16x16x32_bf16(qf[mi][0], kf[nt][0], zf, 0, 0, 0);
                sc[mi][nt] = __builtin_amdgcn_mfma_f32_16x16x32_bf16(qf[mi][1], kf[nt][1], c, 0, 0, 0);
            }
        float mf[4];
        #pragma unroll
        for (int nt = 0; nt < 4; nt++) mf[nt] = msk[kc * 64 + nt * 16 + l16];
        #pragma unroll
        for (int mi = 0; mi < 4; mi++)
            #pragma unroll
            for (int nt = 0; nt < 4; nt++)
                #pragma unroll
                for (int r = 0; r < 4; r++)
                    sc[mi][nt][r] = sc[mi][nt][r] * scale + mf[nt];

        // ---- online softmax per row (row = quad*4+r of qtile mi)
        #pragma unroll
        for (int mi = 0; mi < 4; mi++) {
            #pragma unroll
            for (int r = 0; r < 4; r++) {
                float rm = fmaxf(fmaxf(sc[mi][0][r], sc[mi][1][r]), fmaxf(sc[mi][2][r], sc[mi][3][r]));
                #pragma unroll
                for (int off = 1; off < 16; off <<= 1) rm = fmaxf(rm, __shfl_xor(rm, off));
                float mnew = fmaxf(m_st[mi][r], rm);
                float corr = __expf(m_st[mi][r] - mnew);
                m_st[mi][r] = mnew;
                int qq = mi * 16 + quad * 4 + r;
                float psum = 0.f;
                #pragma unroll
                for (int nt = 0; nt < 4; nt++) {
                    float p = __expf(sc[mi][nt][r] - mnew);
                    psum += p;
                    myP[qq * 64 + (((nt * 2 + (l16 >> 3)) ^ (qq & 7)) * 8) + (l16 & 7)] = f2bf_s(p);
                }
                #pragma unroll
                for (int off = 1; off < 16; off <<= 1) psum += __shfl_xor(psum, off);
                l_st[mi][r] = l_st[mi][r] * corr + psum;
                #pragma unroll
                for (int nt = 0; nt < 4; nt++) accO[mi][nt][r] *= corr;
            }
        }
        __syncthreads();   // sP visible to own wave (lgkm drain) / staging done

        // ---- PV
        bf16x8 pf[4][2], vf[4][2];
        #pragma unroll
        for (int mi = 0; mi < 4; mi++)
            #pragma unroll
            for (int s = 0; s < 2; s++)
                pf[mi][s] = *(bf16x8*)&myP[(mi * 16 + l16) * 64 + (((s * 4 + quad) ^ (l16 & 7)) * 8)];
        #pragma unroll
        for (int nt = 0; nt < 4; nt++)
            #pragma unroll
            for (int s = 0; s < 2; s++)
                vf[nt][s] = *(bf16x8*)&sVT[(nt * 16 + l16) * 64 + (((s * 4 + quad) ^ (l16 & 7)) * 8)];
        #pragma unroll
        for (int mi = 0; mi < 4; mi++)
            #pragma unroll
            for (int nt = 0; nt < 4; nt++) {
                accO[mi][nt] = __builtin_amdgcn_mfma_f32_16x16x32_bf16(pf[mi][0], vf[nt][0], accO[mi][nt], 0, 0, 0);
                accO[mi][nt] = __builtin_amdgcn_mfma_f32_16x16x32_bf16(pf[mi][1], vf[nt][1], accO[mi][nt], 0, 0, 0);
            }
        __syncthreads();   // all waves done with sK/sVT before next staging
    }

    // ---- epilogue: O /= l, scatter to (b,s,D) bf16
    #pragma unroll
    for (int mi = 0; mi < 4; mi++) {
        #pragma unroll
        for (int r = 0; r < 4; r++) {
            float inv = 1.f / l_st[mi][r];
            int row = qb0 + mi * 16 + quad * 4 + r;
            __hip_bfloat16* orow = ao + ((size_t)(b * SEQ + row)) * D_MODEL + hh * HS;
            #pragma unroll
            for (int nt = 0; nt < 4; nt++)
                orow[nt * 16 + l16] = __float2bfloat16(accO[mi][nt][r] * inv);
        }
    }
}

// ---------------------------------------------------------------- tiny FC (f32)
__global__ void fc_kernel(const float* __restrict__ A, const float* __restrict__ W,
                          const float* __restrict__ bias, float* __restrict__ out,
                          int K, int N, int relu)
{
    int row = blockIdx.x;
    int col = blockIdx.y * blockDim.x + threadIdx.x;
    if (col >= N) return;
    const float* a = A + (size_t)row * K;
    float s = 0.f;
    for (int kk = 0; kk < K; kk++) s = fmaf(a[kk], W[(size_t)kk * N + col], s);
    s += bias[col];
    if (relu) s = fmaxf(s, 0.f);
    out[(size_t)row * N + col] = s;
}

// ---------------------------------------------------------------- launch
extern "C" void kernel_launch(void* const* d_in, const int* in_sizes, int n_in,
                              void* d_out, int out_size, void* d_ws, size_t ws_size,
                              hipStream_t stream)
{
    const int*   x     = (const int*)  d_in[0];
    const int*   amask = (const int*)  d_in[1];
    const float* tok   = (const float*)d_in[2];
    const float* pos   = (const float*)d_in[3];
    const float* Wq    = (const float*)d_in[4];
    const float* Wk    = (const float*)d_in[5];
    const float* Wv    = (const float*)d_in[6];
    const float* Wo    = (const float*)d_in[7];
    const float* bo    = (const float*)d_in[8];
    const float* ln1w  = (const float*)d_in[9];
    const float* ln1b  = (const float*)d_in[10];
    const float* ln2w  = (const float*)d_in[11];
    const float* ln2b  = (const float*)d_in[12];
    const float* W1    = (const float*)d_in[13];
    const float* b1    = (const float*)d_in[14];
    const float* W2    = (const float*)d_in[15];
    const float* b2    = (const float*)d_in[16];
    const float* lnfw  = (const float*)d_in[17];
    const float* lnfb  = (const float*)d_in[18];
    const float* cW1   = (const float*)d_in[19];
    const float* cb1   = (const float*)d_in[20];
    const float* cW2   = (const float*)d_in[21];
    const float* cb2   = (const float*)d_in[22];

    char* base = (char*)d_ws;
    float* h = (float*)base;                         base += (size_t)MROWS * D_MODEL * 4;
    __hip_bfloat16* xn = (__hip_bfloat16*)base;      base += (size_t)MROWS * D_MODEL * 2;
    __hip_bfloat16* qb = (__hip_bfloat16*)base;      base += (size_t)MROWS * D_MODEL * 2;
    __hip_bfloat16* kb = (__hip_bfloat16*)base;      base += (size_t)MROWS * D_MODEL * 2;
    __hip_bfloat16* vb = (__hip_bfloat16*)base;      base += (size_t)MROWS * D_MODEL * 2;
    __hip_bfloat16* ff = (__hip_bfloat16*)base;      base += (size_t)MROWS * DFF * 2;
    float* lnf = (float*)base;                       base += (size_t)NB * D_MODEL * 4;
    float* cls = (float*)base;                       base += (size_t)NB * DFF * 4;
    __hip_bfloat16* wTq = (__hip_bfloat16*)base;     base += (size_t)NLAYER * D_MODEL * D_MODEL * 2;
    __hip_bfloat16* wTk = (__hip_bfloat16*)base;     base += (size_t)NLAYER * D_MODEL * D_MODEL * 2;
    __hip_bfloat16* wTv = (__hip_bfloat16*)base;     base += (size_t)NLAYER * D_MODEL * D_MODEL * 2;
    __hip_bfloat16* wTo = (__hip_bfloat16*)base;     base += (size_t)NLAYER * D_MODEL * D_MODEL * 2;
    __hip_bfloat16* wT1 = (__hip_bfloat16*)base;     base += (size_t)NLAYER * D_MODEL * DFF * 2;
    __hip_bfloat16* wT2 = (__hip_bfloat16*)base;     base += (size_t)NLAYER * DFF * D_MODEL * 2;

    const size_t SQW = (size_t)D_MODEL * D_MODEL;
    const size_t SFF = (size_t)D_MODEL * DFF;

    convw_kernel<1><<<dim3(12,12,4), 256, 0, stream>>>(Wq, wTq, D_MODEL, D_MODEL, SQW, SQW);
    convw_kernel<1><<<dim3(12,12,4), 256, 0, stream>>>(Wk, wTk, D_MODEL, D_MODEL, SQW, SQW);
    convw_kernel<1><<<dim3(12,12,4), 256, 0, stream>>>(Wv, wTv, D_MODEL, D_MODEL, SQW, SQW);
    convw_kernel<0><<<dim3(12,12,4), 256, 0, stream>>>(Wo, wTo, D_MODEL, D_MODEL, SQW, SQW);
    convw_kernel<0><<<dim3(12,48,4), 256, 0, stream>>>(W1, wT1, D_MODEL, DFF, SFF, SFF);
    convw_kernel<0><<<dim3(48,12,4), 256, 0, stream>>>(W2, wT2, DFF, D_MODEL, SFF, SFF);

    embed_kernel<<<MROWS, 256, 0, stream>>>(x, tok, pos, h);

    dim3 gD(MROWS / 64, D_MODEL / 128);
    dim3 gF(MROWS / 128, DFF / 128);
    for (int l = 0; l < NLAYER; l++) {
        ln_kernel<1><<<MROWS, 256, 0, stream>>>(h, ln1w + l * D_MODEL, ln1b + l * D_MODEL, xn, 1, 0);
        gemm_bf16<64,1><<<gD, 256, 0, stream>>>(xn, wTq + l * SQW, nullptr, nullptr, qb, MROWS, D_MODEL, D_MODEL, 0);
        gemm_bf16<64,1><<<gD, 256, 0, stream>>>(xn, wTk + l * SQW, nullptr, nullptr, kb, MROWS, D_MODEL, D_MODEL, 0);
        gemm_bf16<64,1><<<gD, 256, 0, stream>>>(xn, wTv + l * SQW, nullptr, nullptr, vb, MROWS, D_MODEL, D_MODEL, 0);
        attn_mfma_kernel<<<NB * NHEAD * 4, 256, 0, stream>>>(qb, kb, vb, amask, xn);
        gemm_bf16<64,0><<<gD, 256, 0, stream>>>(xn, wTo + l * SQW, bo + l * D_MODEL, h, h, MROWS, D_MODEL, D_MODEL, 0);
        ln_kernel<1><<<MROWS, 256, 0, stream>>>(h, ln2w + l * D_MODEL, ln2b + l * D_MODEL, xn, 1, 0);
        gemm_bf16<128,2><<<gF, 256, 0, stream>>>(xn, wT1 + l * SFF, b1 + l * DFF, nullptr, ff, MROWS, DFF, D_MODEL, 1);
        gemm_bf16<64,0><<<gD, 256, 0, stream>>>(ff, wT2 + l * SFF, b2 + l * D_MODEL, h, h, MROWS, D_MODEL, DFF, 0);
    }
    ln_kernel<0><<<NB, 256, 0, stream>>>(h, lnfw, lnfb, lnf, SEQ, SEQ - 1);
    fc_kernel<<<dim3(NB, DFF / 256), 256, 0, stream>>>(lnf, cW1, cb1, cls, D_MODEL, DFF, 1);
    fc_kernel<<<dim3(NB, 1), 64, 0, stream>>>(cls, cW2, cb2, (float*)d_out, DFF, NCLS, 0);
}

// Round 4
// 2344.644 us; speedup vs baseline: 7.1641x; 1.9180x over previous
//
#include <hip/hip_runtime.h>
#include <hip/hip_bf16.h>

#define D_MODEL 768
#define SEQ     1024
#define NB      8
#define NHEAD   12
#define HS      64
#define NLAYER  4
#define DFF     3072
#define NCLS    16
#define MROWS   (NB*SEQ)   // 8192

typedef float f32x4  __attribute__((ext_vector_type(4)));
typedef short bf16x8 __attribute__((ext_vector_type(8)));

__device__ __forceinline__ short f2bf_s(float x) {
    __hip_bfloat16 h = __float2bfloat16(x);
    union { __hip_bfloat16 h; short s; } u; u.h = h; return u.s;
}

// async global->LDS, 16B per lane; lds base must be wave-uniform (HW adds lane*16)
__device__ __forceinline__ void gld16(const void* g, void* l) {
    __builtin_amdgcn_global_load_lds((const __attribute__((address_space(1))) void*)g,
                                     (__attribute__((address_space(3))) void*)l, 16, 0, 0);
}

// ---------------------------------------------------------------- embedding
__global__ __launch_bounds__(256) void embed_kernel(
    const int* __restrict__ x, const float* __restrict__ tok,
    const float* __restrict__ pos, float* __restrict__ h)
{
    int row = blockIdx.x;
    int s   = row & (SEQ - 1);
    int t   = threadIdx.x;
    int id  = x[row];
    const float* te = tok + (size_t)id * D_MODEL;
    const float* pe = pos + (size_t)s  * D_MODEL;
    float* hr = h + (size_t)row * D_MODEL;
    for (int d = t; d < D_MODEL; d += 256) hr[d] = te[d] + pe[d];
}

// ---------------------------------------------------------------- layernorm
template<int BF16OUT>
__global__ __launch_bounds__(256) void ln_kernel(
    const float* __restrict__ in, const float* __restrict__ w,
    const float* __restrict__ b, void* __restrict__ outv,
    int row_stride, int row_offset)
{
    __shared__ float red[256];
    int r = blockIdx.x;
    const float* xr = in + (size_t)(r * row_stride + row_offset) * D_MODEL;
    int t = threadIdx.x;
    float v0 = xr[t], v1 = xr[t + 256], v2 = xr[t + 512];
    red[t] = v0 + v1 + v2; __syncthreads();
    for (int off = 128; off; off >>= 1) { if (t < off) red[t] += red[t + off]; __syncthreads(); }
    float mu = red[0] * (1.f / D_MODEL);
    __syncthreads();
    float d0 = v0 - mu, d1 = v1 - mu, d2 = v2 - mu;
    red[t] = d0*d0 + d1*d1 + d2*d2; __syncthreads();
    for (int off = 128; off; off >>= 1) { if (t < off) red[t] += red[t + off]; __syncthreads(); }
    float rstd = rsqrtf(red[0] * (1.f / D_MODEL) + 1e-5f);
    float y0 = d0 * rstd * w[t]       + b[t];
    float y1 = d1 * rstd * w[t + 256] + b[t + 256];
    float y2 = d2 * rstd * w[t + 512] + b[t + 512];
    if (BF16OUT) {
        __hip_bfloat16* yr = (__hip_bfloat16*)outv + (size_t)r * D_MODEL;
        yr[t] = __float2bfloat16(y0); yr[t+256] = __float2bfloat16(y1); yr[t+512] = __float2bfloat16(y2);
    } else {
        float* yr = (float*)outv + (size_t)r * D_MODEL;
        yr[t] = y0; yr[t+256] = y1; yr[t+512] = y2;
    }
}

// --------------------------------------------- weight convert+transpose to bf16
template<int MODE>
__global__ __launch_bounds__(256) void convw_kernel(
    const float* __restrict__ W, __hip_bfloat16* __restrict__ BT,
    int K, int N, size_t in_stride, size_t out_stride)
{
    __shared__ __hip_bfloat16 sT[64][72];
    W  += (size_t)blockIdx.z * in_stride;
    BT += (size_t)blockIdx.z * out_stride;
    int k0 = blockIdx.x * 64, n0 = blockIdx.y * 64;
    int t = threadIdx.x;
    int kl = t >> 4, nl4 = (t & 15) * 4;
    #pragma unroll
    for (int i = 0; i < 4; i++) {
        int k = k0 + kl + i * 16;
        int n = n0 + nl4;
        const float* src = (MODE == 0) ? (W + (size_t)k * N + n)
                                       : (W + ((size_t)(n >> 6) * K + k) * 64 + (n & 63));
        float4 v = *(const float4*)src;
        sT[nl4 + 0][kl + i*16] = __float2bfloat16(v.x);
        sT[nl4 + 1][kl + i*16] = __float2bfloat16(v.y);
        sT[nl4 + 2][kl + i*16] = __float2bfloat16(v.z);
        sT[nl4 + 3][kl + i*16] = __float2bfloat16(v.w);
    }
    __syncthreads();
    int nl = t >> 2, seg = (t & 3) * 16;
    uint4* dst = (uint4*)(BT + (size_t)(n0 + nl) * K + k0 + seg);
    dst[0] = *(uint4*)&sT[nl][seg];
    dst[1] = *(uint4*)&sT[nl][seg + 8];
}

// ---------------------------------------------------------------- bf16 MFMA GEMM (m97 structure)
// 128x128 tile, BK=32, global_load_lds width=16, XOR-swizzled LDS.
// LDS layout (shorts): row r holds k0..k0+31 as 4 segs of 8; seg s stored at
//   r*32 + ((s ^ key(r))*8), key(r) = (r&3)^((r>>2)&3)  -> 2-way (free) banks.
// Staging: lane L of wave w targets LDS slot chunk*512 + L*8 (HW: base+lane*16);
//   row = chunk*16 + (L>>2), stored seg s' = L&3, so lane loads global seg
//   s = s' ^ key(row). Per-64B-row coalescing preserved (seg permutation).
// OMODE 0: C f32 row-major (+bias,+res).  1: bf16 QKV scatter (Cv=q, k/v at +MD,+2MD).
// OMODE 2: C bf16 row-major (+bias, relu).
template<int OMODE>
__global__ __launch_bounds__(256, 3) void gemm128(
    const __hip_bfloat16* __restrict__ A, const __hip_bfloat16* __restrict__ BT,
    const float* __restrict__ bias, const float* __restrict__ res,
    void* __restrict__ Cv, int M, int N, int K, int relu)
{
    __shared__ short sA[128 * 32];
    __shared__ short sB[128 * 32];
    int t = threadIdx.x;
    int wave = t >> 6, lane = t & 63;
    int l16 = lane & 15, quad = (lane >> 4) & 3;
    int wm = wave >> 1, wn = wave & 1;
    int bm = blockIdx.x * 128, bn = blockIdx.y * 128;

    // staging geometry (wave-uniform chunks; per-lane global seg swizzle)
    int u = lane >> 2;
    int skey = ((u & 3) ^ ((u >> 2) & 3));
    int sseg = (lane & 3) ^ skey;
    int c0 = wave * 2, c1 = wave * 2 + 1;
    int rA0 = c0 * 16 + u, rA1 = c1 * 16 + u;
    // frag-read key (same formula, row = base16 + l16)
    int fkey = ((l16 & 3) ^ ((l16 >> 2) & 3));

    const f32x4 zf = {0.f, 0.f, 0.f, 0.f};
    f32x4 acc[4][4];
    #pragma unroll
    for (int mi = 0; mi < 4; mi++)
        #pragma unroll
        for (int ni = 0; ni < 4; ni++) acc[mi][ni] = zf;

    for (int k0 = 0; k0 < K; k0 += 32) {
        gld16(A  + (size_t)(bm + rA0) * K + k0 + sseg * 8, &sA[c0 * 512]);
        gld16(A  + (size_t)(bm + rA1) * K + k0 + sseg * 8, &sA[c1 * 512]);
        gld16(BT + (size_t)(bn + rA0) * K + k0 + sseg * 8, &sB[c0 * 512]);
        gld16(BT + (size_t)(bn + rA1) * K + k0 + sseg * 8, &sB[c1 * 512]);
        __syncthreads();   // drains vmcnt before barrier
        bf16x8 aF[4], bF[4];
        #pragma unroll
        for (int mi = 0; mi < 4; mi++)
            aF[mi] = *(bf16x8*)&sA[(wm * 64 + mi * 16 + l16) * 32 + ((quad ^ fkey) * 8)];
        #pragma unroll
        for (int ni = 0; ni < 4; ni++)
            bF[ni] = *(bf16x8*)&sB[(wn * 64 + ni * 16 + l16) * 32 + ((quad ^ fkey) * 8)];
        #pragma unroll
        for (int ni = 0; ni < 4; ni++)
            #pragma unroll
            for (int mi = 0; mi < 4; mi++)
                acc[mi][ni] = __builtin_amdgcn_mfma_f32_16x16x32_bf16(aF[mi], bF[ni], acc[mi][ni], 0, 0, 0);
        __syncthreads();
    }
    #pragma unroll
    for (int mi = 0; mi < 4; mi++) {
        #pragma unroll
        for (int ni = 0; ni < 4; ni++) {
            int row0 = bm + wm * 64 + mi * 16 + quad * 4;
            int col  = bn + wn * 64 + ni * 16 + l16;
            #pragma unroll
            for (int r = 0; r < 4; r++) {
                int row = row0 + r;
                float v = acc[mi][ni][r];
                if (OMODE != 1 && bias) v += bias[col];
                if (relu) v = fmaxf(v, 0.f);
                if (OMODE == 0) {
                    float* C = (float*)Cv;
                    if (res) v += res[(size_t)row * N + col];
                    C[(size_t)row * N + col] = v;
                } else if (OMODE == 1) {
                    int which = col / D_MODEL, cc = col % D_MODEL;
                    int bb = row >> 10, ss = row & 1023, hh = cc >> 6, e = cc & 63;
                    ((__hip_bfloat16*)Cv)[(size_t)which * MROWS * D_MODEL +
                        (((size_t)(bb * NHEAD + hh)) * SEQ + ss) * HS + e] = __float2bfloat16(v);
                } else {
                    ((__hip_bfloat16*)Cv)[(size_t)row * N + col] = __float2bfloat16(v);
                }
            }
        }
    }
    (void)M;
}

// ---------------------------------------------------------------- MFMA flash attention
__global__ __launch_bounds__(256, 1) void attn_mfma_kernel(
    const __hip_bfloat16* __restrict__ q, const __hip_bfloat16* __restrict__ k,
    const __hip_bfloat16* __restrict__ v, const int* __restrict__ mask,
    __hip_bfloat16* __restrict__ ao)
{
    __shared__ short sK[64 * 64];
    __shared__ short sVT[64 * 64];
    __shared__ short sP[4][64 * 64];
    __shared__ float msk[SEQ];
    int blk = blockIdx.x;
    int qt = blk & 3, bh = blk >> 2;
    int b = bh / NHEAD, hh = bh % NHEAD;
    int t = threadIdx.x, wave = t >> 6, lane = t & 63;
    int l16 = lane & 15, quad = lane >> 4;
    const float scale = 0.036084391824351615f;  // 768^-0.5
    const f32x4 zf = {0.f, 0.f, 0.f, 0.f};

    #pragma unroll
    for (int i = 0; i < 4; i++) {
        int idx = t + i * 256;
        msk[idx] = mask[b * SEQ + idx] ? 0.f : -1e30f;
    }

    int qb0 = qt * 256 + wave * 64;
    const __hip_bfloat16* qbase = q + ((size_t)bh * SEQ + qb0) * HS;
    bf16x8 qf[4][2];
    #pragma unroll
    for (int mi = 0; mi < 4; mi++)
        #pragma unroll
        for (int s = 0; s < 2; s++)
            qf[mi][s] = *(const bf16x8*)(qbase + (mi * 16 + l16) * HS + s * 32 + quad * 8);

    f32x4 accO[4][4];
    float m_st[4][4], l_st[4][4];
    #pragma unroll
    for (int mi = 0; mi < 4; mi++) {
        #pragma unroll
        for (int nt = 0; nt < 4; nt++) accO[mi][nt] = zf;
        #pragma unroll
        for (int r = 0; r < 4; r++) { m_st[mi][r] = -1e30f; l_st[mi][r] = 0.f; }
    }

    short* myP = &sP[wave][0];
    for (int kc = 0; kc < 16; kc++) {
        const __hip_bfloat16* kg = k + ((size_t)bh * SEQ + kc * 64) * HS;
        const __hip_bfloat16* vg = v + ((size_t)bh * SEQ + kc * 64) * HS;
        #pragma unroll
        for (int i = 0; i < 2; i++) {
            int idx = t + i * 256;
            int key = idx >> 3, seg = idx & 7;
            uint4 kv = *(const uint4*)(kg + key * HS + seg * 8);
            *(uint4*)&sK[key * 64 + ((seg ^ (key & 7)) * 8)] = kv;
            union { uint4 u; short s[8]; } vu;
            vu.u = *(const uint4*)(vg + key * HS + seg * 8);
            #pragma unroll
            for (int jj = 0; jj < 8; jj++) {
                int dim = seg * 8 + jj;
                sVT[dim * 64 + (((key >> 3) ^ jj) * 8) + (key & 7)] = vu.s[jj];
            }
        }
        __syncthreads();

        bf16x8 kf[4][2];
        #pragma unroll
        for (int nt = 0; nt < 4; nt++)
            #pragma unroll
            for (int s = 0; s < 2; s++)
                kf[nt][s] = *(bf16x8*)&sK[(nt * 16 + l16) * 64 + (((s * 4 + quad) ^ (l16 & 7)) * 8)];
        f32x4 sc[4][4];
        #pragma unroll
        for (int mi = 0; mi < 4; mi++)
            #pragma unroll
            for (int nt = 0; nt < 4; nt++) {
                f32x4 c = __builtin_amdgcn_mfma_f32_16x16x32_bf16(qf[mi][0], kf[nt][0], zf, 0, 0, 0);
                sc[mi][nt] = __builtin_amdgcn_mfma_f32_16x16x32_bf16(qf[mi][1], kf[nt][1], c, 0, 0, 0);
            }
        float mf[4];
        #pragma unroll
        for (int nt = 0; nt < 4; nt++) mf[nt] = msk[kc * 64 + nt * 16 + l16];
        #pragma unroll
        for (int mi = 0; mi < 4; mi++)
            #pragma unroll
            for (int nt = 0; nt < 4; nt++)
                #pragma unroll
                for (int r = 0; r < 4; r++)
                    sc[mi][nt][r] = sc[mi][nt][r] * scale + mf[nt];

        #pragma unroll
        for (int mi = 0; mi < 4; mi++) {
            #pragma unroll
            for (int r = 0; r < 4; r++) {
                float rm = fmaxf(fmaxf(sc[mi][0][r], sc[mi][1][r]), fmaxf(sc[mi][2][r], sc[mi][3][r]));
                #pragma unroll
                for (int off = 1; off < 16; off <<= 1) rm = fmaxf(rm, __shfl_xor(rm, off));
                float mnew = fmaxf(m_st[mi][r], rm);
                float corr = __expf(m_st[mi][r] - mnew);
                m_st[mi][r] = mnew;
                int qq = mi * 16 + quad * 4 + r;
                float psum = 0.f;
                #pragma unroll
                for (int nt = 0; nt < 4; nt++) {
                    float p = __expf(sc[mi][nt][r] - mnew);
                    psum += p;
                    myP[qq * 64 + (((nt * 2 + (l16 >> 3)) ^ (qq & 7)) * 8) + (l16 & 7)] = f2bf_s(p);
                }
                #pragma unroll
                for (int off = 1; off < 16; off <<= 1) psum += __shfl_xor(psum, off);
                l_st[mi][r] = l_st[mi][r] * corr + psum;
                #pragma unroll
                for (int nt = 0; nt < 4; nt++) accO[mi][nt][r] *= corr;
            }
        }
        __syncthreads();

        bf16x8 pf[4][2], vf[4][2];
        #pragma unroll
        for (int mi = 0; mi < 4; mi++)
            #pragma unroll
            for (int s = 0; s < 2; s++)
                pf[mi][s] = *(bf16x8*)&myP[(mi * 16 + l16) * 64 + (((s * 4 + quad) ^ (l16 & 7)) * 8)];
        #pragma unroll
        for (int nt = 0; nt < 4; nt++)
            #pragma unroll
            for (int s = 0; s < 2; s++)
                vf[nt][s] = *(bf16x8*)&sVT[(nt * 16 + l16) * 64 + (((s * 4 + quad) ^ (l16 & 7)) * 8)];
        #pragma unroll
        for (int mi = 0; mi < 4; mi++)
            #pragma unroll
            for (int nt = 0; nt < 4; nt++) {
                accO[mi][nt] = __builtin_amdgcn_mfma_f32_16x16x32_bf16(pf[mi][0], vf[nt][0], accO[mi][nt], 0, 0, 0);
                accO[mi][nt] = __builtin_amdgcn_mfma_f32_16x16x32_bf16(pf[mi][1], vf[nt][1], accO[mi][nt], 0, 0, 0);
            }
        __syncthreads();
    }

    #pragma unroll
    for (int mi = 0; mi < 4; mi++) {
        #pragma unroll
        for (int r = 0; r < 4; r++) {
            float inv = 1.f / l_st[mi][r];
            int row = qb0 + mi * 16 + quad * 4 + r;
            __hip_bfloat16* orow = ao + ((size_t)(b * SEQ + row)) * D_MODEL + hh * HS;
            #pragma unroll
            for (int nt = 0; nt < 4; nt++)
                orow[nt * 16 + l16] = __float2bfloat16(accO[mi][nt][r] * inv);
        }
    }
}

// ---------------------------------------------------------------- head FC1: (8,768)@(768,3072)+relu
__global__ __launch_bounds__(256) void fc1_kernel(
    const float* __restrict__ A, const float* __restrict__ W,
    const float* __restrict__ bias, float* __restrict__ out)
{
    __shared__ float sa[D_MODEL];
    int row = blockIdx.x, t = threadIdx.x;
    for (int i = t; i < D_MODEL; i += 256) sa[i] = A[(size_t)row * D_MODEL + i];
    __syncthreads();
    int col = blockIdx.y * 256 + t;
    float s = 0.f;
    #pragma unroll 8
    for (int kk = 0; kk < D_MODEL; kk++) s = fmaf(sa[kk], W[(size_t)kk * DFF + col], s);
    s += bias[col];
    out[(size_t)row * DFF + col] = fmaxf(s, 0.f);
}

// ---------------------------------------------------------------- head FC2: (8,3072)@(3072,16)
__global__ __launch_bounds__(256) void fc2_kernel(
    const float* __restrict__ A, const float* __restrict__ W,
    const float* __restrict__ bias, float* __restrict__ out)
{
    __shared__ float wred[4][NCLS];
    int row = blockIdx.x, t = threadIdx.x;
    int wave = t >> 6, lane = t & 63;
    const float* a = A + (size_t)row * DFF;
    float acc[NCLS];
    #pragma unroll
    for (int c = 0; c < NCLS; c++) acc[c] = 0.f;
    for (int kk = t; kk < DFF; kk += 256) {
        float av = a[kk];
        const float4* wr = (const float4*)(W + (size_t)kk * NCLS);
        float4 w0 = wr[0], w1 = wr[1], w2 = wr[2], w3 = wr[3];
        acc[0]  = fmaf(av, w0.x, acc[0]);  acc[1]  = fmaf(av, w0.y, acc[1]);
        acc[2]  = fmaf(av, w0.z, acc[2]);  acc[3]  = fmaf(av, w0.w, acc[3]);
        acc[4]  = fmaf(av, w1.x, acc[4]);  acc[5]  = fmaf(av, w1.y, acc[5]);
        acc[6]  = fmaf(av, w1.z, acc[6]);  acc[7]  = fmaf(av, w1.w, acc[7]);
        acc[8]  = fmaf(av, w2.x, acc[8]);  acc[9]  = fmaf(av, w2.y, acc[9]);
        acc[10] = fmaf(av, w2.z, acc[10]); acc[11] = fmaf(av, w2.w, acc[11]);
        acc[12] = fmaf(av, w3.x, acc[12]); acc[13] = fmaf(av, w3.y, acc[13]);
        acc[14] = fmaf(av, w3.z, acc[14]); acc[15] = fmaf(av, w3.w, acc[15]);
    }
    #pragma unroll
    for (int c = 0; c < NCLS; c++)
        #pragma unroll
        for (int off = 32; off; off >>= 1) acc[c] += __shfl_down(acc[c], off);
    if (lane == 0)
        #pragma unroll
        for (int c = 0; c < NCLS; c++) wred[wave][c] = acc[c];
    __syncthreads();
    if (t < NCLS)
        out[row * NCLS + t] = wred[0][t] + wred[1][t] + wred[2][t] + wred[3][t] + bias[t];
}

// ---------------------------------------------------------------- launch
extern "C" void kernel_launch(void* const* d_in, const int* in_sizes, int n_in,
                              void* d_out, int out_size, void* d_ws, size_t ws_size,
                              hipStream_t stream)
{
    const int*   x     = (const int*)  d_in[0];
    const int*   amask = (const int*)  d_in[1];
    const float* tok   = (const float*)d_in[2];
    const float* pos   = (const float*)d_in[3];
    const float* Wq    = (const float*)d_in[4];
    const float* Wk    = (const float*)d_in[5];
    const float* Wv    = (const float*)d_in[6];
    const float* Wo    = (const float*)d_in[7];
    const float* bo    = (const float*)d_in[8];
    const float* ln1w  = (const float*)d_in[9];
    const float* ln1b  = (const float*)d_in[10];
    const float* ln2w  = (const float*)d_in[11];
    const float* ln2b  = (const float*)d_in[12];
    const float* W1    = (const float*)d_in[13];
    const float* b1    = (const float*)d_in[14];
    const float* W2    = (const float*)d_in[15];
    const float* b2    = (const float*)d_in[16];
    const float* lnfw  = (const float*)d_in[17];
    const float* lnfb  = (const float*)d_in[18];
    const float* cW1   = (const float*)d_in[19];
    const float* cb1   = (const float*)d_in[20];
    const float* cW2   = (const float*)d_in[21];
    const float* cb2   = (const float*)d_in[22];

    char* base = (char*)d_ws;
    const size_t MD = (size_t)MROWS * D_MODEL;
    float* h = (float*)base;                         base += MD * 4;
    __hip_bfloat16* xn = (__hip_bfloat16*)base;      base += MD * 2;
    __hip_bfloat16* qb = (__hip_bfloat16*)base;      base += MD * 2;   // k at +MD, v at +2MD
    __hip_bfloat16* kb = (__hip_bfloat16*)base;      base += MD * 2;
    __hip_bfloat16* vb = (__hip_bfloat16*)base;      base += MD * 2;
    __hip_bfloat16* ff = (__hip_bfloat16*)base;      base += (size_t)MROWS * DFF * 2;
    float* lnf = (float*)base;                       base += (size_t)NB * D_MODEL * 4;
    float* cls = (float*)base;                       base += (size_t)NB * DFF * 4;
    __hip_bfloat16* wQKV = (__hip_bfloat16*)base;    base += (size_t)NLAYER * 3 * D_MODEL * D_MODEL * 2;
    __hip_bfloat16* wTo = (__hip_bfloat16*)base;     base += (size_t)NLAYER * D_MODEL * D_MODEL * 2;
    __hip_bfloat16* wT1 = (__hip_bfloat16*)base;     base += (size_t)NLAYER * D_MODEL * DFF * 2;
    __hip_bfloat16* wT2 = (__hip_bfloat16*)base;     base += (size_t)NLAYER * DFF * D_MODEL * 2;

    const size_t SQW = (size_t)D_MODEL * D_MODEL;
    const size_t SFF = (size_t)D_MODEL * DFF;

    // QKV weights stacked per layer: [l][which*768 + n][k]
    convw_kernel<1><<<dim3(12,12,4), 256, 0, stream>>>(Wq, wQKV + 0 * SQW, D_MODEL, D_MODEL, SQW, 3 * SQW);
    convw_kernel<1><<<dim3(12,12,4), 256, 0, stream>>>(Wk, wQKV + 1 * SQW, D_MODEL, D_MODEL, SQW, 3 * SQW);
    convw_kernel<1><<<dim3(12,12,4), 256, 0, stream>>>(Wv, wQKV + 2 * SQW, D_MODEL, D_MODEL, SQW, 3 * SQW);
    convw_kernel<0><<<dim3(12,12,4), 256, 0, stream>>>(Wo, wTo, D_MODEL, D_MODEL, SQW, SQW);
    convw_kernel<0><<<dim3(12,48,4), 256, 0, stream>>>(W1, wT1, D_MODEL, DFF, SFF, SFF);
    convw_kernel<0><<<dim3(48,12,4), 256, 0, stream>>>(W2, wT2, DFF, D_MODEL, SFF, SFF);

    embed_kernel<<<MROWS, 256, 0, stream>>>(x, tok, pos, h);

    dim3 gQKV(MROWS / 128, (3 * D_MODEL) / 128);   // (64, 18)
    dim3 gD(MROWS / 128, D_MODEL / 128);           // (64, 6)
    dim3 gF(MROWS / 128, DFF / 128);               // (64, 24)
    for (int l = 0; l < NLAYER; l++) {
        ln_kernel<1><<<MROWS, 256, 0, stream>>>(h, ln1w + l * D_MODEL, ln1b + l * D_MODEL, xn, 1, 0);
        gemm128<1><<<gQKV, 256, 0, stream>>>(xn, wQKV + l * 3 * SQW, nullptr, nullptr, qb, MROWS, 3 * D_MODEL, D_MODEL, 0);
        attn_mfma_kernel<<<NB * NHEAD * 4, 256, 0, stream>>>(qb, kb, vb, amask, xn);
        gemm128<0><<<gD, 256, 0, stream>>>(xn, wTo + l * SQW, bo + l * D_MODEL, h, h, MROWS, D_MODEL, D_MODEL, 0);
        ln_kernel<1><<<MROWS, 256, 0, stream>>>(h, ln2w + l * D_MODEL, ln2b + l * D_MODEL, xn, 1, 0);
        gemm128<2><<<gF, 256, 0, stream>>>(xn, wT1 + l * SFF, b1 + l * DFF, nullptr, ff, MROWS, DFF, D_MODEL, 1);
        gemm128<0><<<gD, 256, 0, stream>>>(ff, wT2 + l * SFF, b2 + l * D_MODEL, h, h, MROWS, D_MODEL, DFF, 0);
    }
    ln_kernel<0><<<NB, 256, 0, stream>>>(h, lnfw, lnfb, lnf, SEQ, SEQ - 1);
    fc1_kernel<<<dim3(NB, DFF / 256), 256, 0, stream>>>(lnf, cW1, cb1, cls);
    fc2_kernel<<<NB, 256, 0, stream>>>(cls, cW2, cb2, (float*)d_out);
}

// Round 5
// 1830.159 us; speedup vs baseline: 9.1781x; 1.2811x over previous
//
#include <hip/hip_runtime.h>
#include <hip/hip_bf16.h>

#define D_MODEL 768
#define SEQ     1024
#define NB      8
#define NHEAD   12
#define HS      64
#define NLAYER  4
#define DFF     3072
#define NCLS    16
#define MROWS   (NB*SEQ)   // 8192

typedef float f32x4  __attribute__((ext_vector_type(4)));
typedef short bf16x8 __attribute__((ext_vector_type(8)));

__device__ __forceinline__ short f2bf_s(float x) {
    __hip_bfloat16 h = __float2bfloat16(x);
    union { __hip_bfloat16 h; short s; } u; u.h = h; return u.s;
}

// async global->LDS, 16B per lane; lds base must be wave-uniform (HW adds lane*16)
__device__ __forceinline__ void gld16(const void* g, void* l) {
    __builtin_amdgcn_global_load_lds((const __attribute__((address_space(1))) void*)g,
                                     (__attribute__((address_space(3))) void*)l, 16, 0, 0);
}

// ---------------------------------------------------------------- embedding
__global__ __launch_bounds__(256) void embed_kernel(
    const int* __restrict__ x, const float* __restrict__ tok,
    const float* __restrict__ pos, float* __restrict__ h)
{
    int row = blockIdx.x;
    int s   = row & (SEQ - 1);
    int t   = threadIdx.x;
    int id  = x[row];
    const float* te = tok + (size_t)id * D_MODEL;
    const float* pe = pos + (size_t)s  * D_MODEL;
    float* hr = h + (size_t)row * D_MODEL;
    for (int d = t; d < D_MODEL; d += 256) hr[d] = te[d] + pe[d];
}

// ---------------------------------------------------------------- layernorm
template<int BF16OUT>
__global__ __launch_bounds__(256) void ln_kernel(
    const float* __restrict__ in, const float* __restrict__ w,
    const float* __restrict__ b, void* __restrict__ outv,
    int row_stride, int row_offset)
{
    __shared__ float red[256];
    int r = blockIdx.x;
    const float* xr = in + (size_t)(r * row_stride + row_offset) * D_MODEL;
    int t = threadIdx.x;
    float v0 = xr[t], v1 = xr[t + 256], v2 = xr[t + 512];
    red[t] = v0 + v1 + v2; __syncthreads();
    for (int off = 128; off; off >>= 1) { if (t < off) red[t] += red[t + off]; __syncthreads(); }
    float mu = red[0] * (1.f / D_MODEL);
    __syncthreads();
    float d0 = v0 - mu, d1 = v1 - mu, d2 = v2 - mu;
    red[t] = d0*d0 + d1*d1 + d2*d2; __syncthreads();
    for (int off = 128; off; off >>= 1) { if (t < off) red[t] += red[t + off]; __syncthreads(); }
    float rstd = rsqrtf(red[0] * (1.f / D_MODEL) + 1e-5f);
    float y0 = d0 * rstd * w[t]       + b[t];
    float y1 = d1 * rstd * w[t + 256] + b[t + 256];
    float y2 = d2 * rstd * w[t + 512] + b[t + 512];
    if (BF16OUT) {
        __hip_bfloat16* yr = (__hip_bfloat16*)outv + (size_t)r * D_MODEL;
        yr[t] = __float2bfloat16(y0); yr[t+256] = __float2bfloat16(y1); yr[t+512] = __float2bfloat16(y2);
    } else {
        float* yr = (float*)outv + (size_t)r * D_MODEL;
        yr[t] = y0; yr[t+256] = y1; yr[t+512] = y2;
    }
}

// --------------------------------------------- weight convert+transpose to bf16
template<int MODE>
__global__ __launch_bounds__(256) void convw_kernel(
    const float* __restrict__ W, __hip_bfloat16* __restrict__ BT,
    int K, int N, size_t in_stride, size_t out_stride)
{
    __shared__ __hip_bfloat16 sT[64][72];
    W  += (size_t)blockIdx.z * in_stride;
    BT += (size_t)blockIdx.z * out_stride;
    int k0 = blockIdx.x * 64, n0 = blockIdx.y * 64;
    int t = threadIdx.x;
    int kl = t >> 4, nl4 = (t & 15) * 4;
    #pragma unroll
    for (int i = 0; i < 4; i++) {
        int k = k0 + kl + i * 16;
        int n = n0 + nl4;
        const float* src = (MODE == 0) ? (W + (size_t)k * N + n)
                                       : (W + ((size_t)(n >> 6) * K + k) * 64 + (n & 63));
        float4 v = *(const float4*)src;
        sT[nl4 + 0][kl + i*16] = __float2bfloat16(v.x);
        sT[nl4 + 1][kl + i*16] = __float2bfloat16(v.y);
        sT[nl4 + 2][kl + i*16] = __float2bfloat16(v.z);
        sT[nl4 + 3][kl + i*16] = __float2bfloat16(v.w);
    }
    __syncthreads();
    int nl = t >> 2, seg = (t & 3) * 16;
    uint4* dst = (uint4*)(BT + (size_t)(n0 + nl) * K + k0 + seg);
    dst[0] = *(uint4*)&sT[nl][seg];
    dst[1] = *(uint4*)&sT[nl][seg + 8];
}

// ---------------------------------------------------------------- bf16 MFMA GEMM (m97 structure)
template<int OMODE>
__global__ __launch_bounds__(256, 3) void gemm128(
    const __hip_bfloat16* __restrict__ A, const __hip_bfloat16* __restrict__ BT,
    const float* __restrict__ bias, const float* __restrict__ res,
    void* __restrict__ Cv, int M, int N, int K, int relu)
{
    __shared__ short sA[128 * 32];
    __shared__ short sB[128 * 32];
    int t = threadIdx.x;
    int wave = t >> 6, lane = t & 63;
    int l16 = lane & 15, quad = (lane >> 4) & 3;
    int wm = wave >> 1, wn = wave & 1;
    int bm = blockIdx.x * 128, bn = blockIdx.y * 128;

    int u = lane >> 2;
    int skey = ((u & 3) ^ ((u >> 2) & 3));
    int sseg = (lane & 3) ^ skey;
    int c0 = wave * 2, c1 = wave * 2 + 1;
    int rA0 = c0 * 16 + u, rA1 = c1 * 16 + u;
    int fkey = ((l16 & 3) ^ ((l16 >> 2) & 3));

    const f32x4 zf = {0.f, 0.f, 0.f, 0.f};
    f32x4 acc[4][4];
    #pragma unroll
    for (int mi = 0; mi < 4; mi++)
        #pragma unroll
        for (int ni = 0; ni < 4; ni++) acc[mi][ni] = zf;

    for (int k0 = 0; k0 < K; k0 += 32) {
        gld16(A  + (size_t)(bm + rA0) * K + k0 + sseg * 8, &sA[c0 * 512]);
        gld16(A  + (size_t)(bm + rA1) * K + k0 + sseg * 8, &sA[c1 * 512]);
        gld16(BT + (size_t)(bn + rA0) * K + k0 + sseg * 8, &sB[c0 * 512]);
        gld16(BT + (size_t)(bn + rA1) * K + k0 + sseg * 8, &sB[c1 * 512]);
        __syncthreads();
        bf16x8 aF[4], bF[4];
        #pragma unroll
        for (int mi = 0; mi < 4; mi++)
            aF[mi] = *(bf16x8*)&sA[(wm * 64 + mi * 16 + l16) * 32 + ((quad ^ fkey) * 8)];
        #pragma unroll
        for (int ni = 0; ni < 4; ni++)
            bF[ni] = *(bf16x8*)&sB[(wn * 64 + ni * 16 + l16) * 32 + ((quad ^ fkey) * 8)];
        #pragma unroll
        for (int ni = 0; ni < 4; ni++)
            #pragma unroll
            for (int mi = 0; mi < 4; mi++)
                acc[mi][ni] = __builtin_amdgcn_mfma_f32_16x16x32_bf16(aF[mi], bF[ni], acc[mi][ni], 0, 0, 0);
        __syncthreads();
    }
    #pragma unroll
    for (int mi = 0; mi < 4; mi++) {
        #pragma unroll
        for (int ni = 0; ni < 4; ni++) {
            int row0 = bm + wm * 64 + mi * 16 + quad * 4;
            int col  = bn + wn * 64 + ni * 16 + l16;
            #pragma unroll
            for (int r = 0; r < 4; r++) {
                int row = row0 + r;
                float v = acc[mi][ni][r];
                if (OMODE != 1 && bias) v += bias[col];
                if (relu) v = fmaxf(v, 0.f);
                if (OMODE == 0) {
                    float* C = (float*)Cv;
                    if (res) v += res[(size_t)row * N + col];
                    C[(size_t)row * N + col] = v;
                } else if (OMODE == 1) {
                    int which = col / D_MODEL, cc = col % D_MODEL;
                    int bb = row >> 10, ss = row & 1023, hh = cc >> 6, e = cc & 63;
                    ((__hip_bfloat16*)Cv)[(size_t)which * MROWS * D_MODEL +
                        (((size_t)(bb * NHEAD + hh)) * SEQ + ss) * HS + e] = __float2bfloat16(v);
                } else {
                    ((__hip_bfloat16*)Cv)[(size_t)row * N + col] = __float2bfloat16(v);
                }
            }
        }
    }
    (void)M;
}

// ---------------------------------------------------------------- V transpose: (bh,s,e) -> (bh,e,s)
__global__ __launch_bounds__(256) void vtrans_kernel(
    const __hip_bfloat16* __restrict__ vb, __hip_bfloat16* __restrict__ vt)
{
    __shared__ short tile[64][66];
    int bh = blockIdx.x, st = blockIdx.y;
    const short* src = (const short*)vb + ((size_t)bh * SEQ + st * 64) * HS;
    int t = threadIdx.x;
    #pragma unroll
    for (int i = 0; i < 2; i++) {
        int slot = t + i * 256;
        int row = slot >> 3, seg = slot & 7;
        *(uint4*)&tile[row][seg * 8] = *(const uint4*)(src + row * HS + seg * 8);
    }
    __syncthreads();
    short* dst = (short*)vt + (size_t)bh * HS * SEQ + st * 64;
    #pragma unroll
    for (int i = 0; i < 2; i++) {
        int slot = t + i * 256;
        int e = slot >> 3, seg = slot & 7;
        union { uint4 u; short s[8]; } pk;
        #pragma unroll
        for (int j = 0; j < 8; j++) pk.s[j] = tile[seg * 8 + j][e];
        *(uint4*)(dst + (size_t)e * SEQ + seg * 8) = pk.u;
    }
}

// ---------------------------------------------------------------- MFMA flash attention v3 (S^T orientation)
// Block = 2 waves = 128 queries of one (b,h); wave owns 64 queries (4 qt-tiles).
// S^T = mfma(A=K-frag, B=Q-frag): C-layout row=key(quad*4+r), col=query(l16)
//  -> per-query softmax: 16 in-lane values + 2 shuffles (xor16/xor32).
//  -> P packs 4 consecutive keys per b64 LDS write; PV: O^T = mfma(A=VT, B=P-rows).
// K/VT staged via global_load_lds w=16 with XOR-seg swizzle: slot L -> global seg
//  (L&7)^((L>>3)&7); frag reads at seg (s*4+quad)^(row&7) -> 2-way (free) banks.
// NOTE: reference scale = D_MODEL^-0.5.
__global__ __launch_bounds__(128, 2) void attn_mfma_kernel(
    const __hip_bfloat16* __restrict__ q, const __hip_bfloat16* __restrict__ k,
    const __hip_bfloat16* __restrict__ v, const int* __restrict__ mask,
    __hip_bfloat16* __restrict__ ao)
{
    __shared__ short sK[64 * 64];
    __shared__ short sVT[64 * 64];
    __shared__ short sP[2][64 * 64];
    __shared__ float mskf[SEQ];
    int blk = blockIdx.x;
    int qt8 = blk & 7, bh = blk >> 3;
    int b = bh / NHEAD, hh = bh % NHEAD;
    int t = threadIdx.x, w = t >> 6, lane = t & 63;
    int l16 = lane & 15, quad = lane >> 4;
    const float scale = 0.036084391824351615f;  // 768^-0.5
    const f32x4 zf = {0.f, 0.f, 0.f, 0.f};

    #pragma unroll
    for (int i = 0; i < 8; i++) {
        int idx = t + i * 128;
        mskf[idx] = mask[b * SEQ + idx] ? 0.f : -1e30f;
    }

    // Q B-frags: lane n=query(l16), k=dim s*32+quad*8..+7
    int qb0 = qt8 * 128 + w * 64;
    const __hip_bfloat16* qbase = q + ((size_t)bh * SEQ + qb0) * HS;
    bf16x8 qf[4][2];
    #pragma unroll
    for (int qt = 0; qt < 4; qt++)
        #pragma unroll
        for (int s = 0; s < 2; s++)
            qf[qt][s] = *(const bf16x8*)(qbase + (qt * 16 + l16) * HS + s * 32 + quad * 8);

    f32x4 accO[4][4];            // [dt][qt]: O^T tile, row=dim dt*16+quad*4+r, col=query qt*16+l16
    float m_st[4], l_st[4];      // per qt (query qt*16+l16)
    #pragma unroll
    for (int dt = 0; dt < 4; dt++)
        #pragma unroll
        for (int qt = 0; qt < 4; qt++) accO[dt][qt] = zf;
    #pragma unroll
    for (int qt = 0; qt < 4; qt++) { m_st[qt] = -1e30f; l_st[qt] = 0.f; }

    // staging geometry
    int rowL = lane >> 3;
    int sgl = ((lane & 7) ^ ((lane >> 3) & 7)) * 8;   // swizzled global seg (shorts)
    const __hip_bfloat16* kg0 = k + ((size_t)bh * SEQ) * HS;
    const __hip_bfloat16* vtg0 = v + (size_t)bh * HS * SEQ;   // v = pre-transposed vT here
    short* myP = &sP[w][0];

    for (int kc = 0; kc < 16; kc++) {
        const __hip_bfloat16* kg = kg0 + (size_t)kc * 64 * HS;
        const __hip_bfloat16* vtg = vtg0 + kc * 64;
        #pragma unroll
        for (int i = 0; i < 4; i++) {
            int c = w * 4 + i;
            int rr = c * 8 + rowL;
            gld16(kg + (size_t)rr * HS + sgl, (char*)sK + c * 1024);
            gld16(vtg + (size_t)rr * SEQ + sgl, (char*)sVT + c * 1024);
        }
        __syncthreads();

        // all sK/sVT reads up front (so the end-of-loop barrier is the only other one)
        bf16x8 vf[4][2];
        #pragma unroll
        for (int dt = 0; dt < 4; dt++)
            #pragma unroll
            for (int s = 0; s < 2; s++)
                vf[dt][s] = *(bf16x8*)&sVT[(dt * 16 + l16) * 64 + (((s * 4 + quad) ^ (l16 & 7)) * 8)];
        f32x4 sc[4][4];   // [kt][qt]
        #pragma unroll
        for (int kt = 0; kt < 4; kt++) {
            bf16x8 kf0 = *(bf16x8*)&sK[(kt * 16 + l16) * 64 + ((quad ^ (l16 & 7)) * 8)];
            bf16x8 kf1 = *(bf16x8*)&sK[(kt * 16 + l16) * 64 + (((4 + quad) ^ (l16 & 7)) * 8)];
            #pragma unroll
            for (int qt = 0; qt < 4; qt++) {
                f32x4 c = __builtin_amdgcn_mfma_f32_16x16x32_bf16(kf0, qf[qt][0], zf, 0, 0, 0);
                sc[kt][qt] = __builtin_amdgcn_mfma_f32_16x16x32_bf16(kf1, qf[qt][1], c, 0, 0, 0);
            }
        }
        // scale + mask (mask indexed by key row)
        #pragma unroll
        for (int kt = 0; kt < 4; kt++) {
            f32x4 mk = *(f32x4*)&mskf[kc * 64 + kt * 16 + quad * 4];
            #pragma unroll
            for (int qt = 0; qt < 4; qt++)
                #pragma unroll
                for (int r = 0; r < 4; r++)
                    sc[kt][qt][r] = sc[kt][qt][r] * scale + mk[r];
        }
        // online softmax per query column
        #pragma unroll
        for (int qt = 0; qt < 4; qt++) {
            float rm = -1e30f;
            #pragma unroll
            for (int kt = 0; kt < 4; kt++)
                #pragma unroll
                for (int r = 0; r < 4; r++) rm = fmaxf(rm, sc[kt][qt][r]);
            rm = fmaxf(rm, __shfl_xor(rm, 16));
            rm = fmaxf(rm, __shfl_xor(rm, 32));
            float mnew = fmaxf(m_st[qt], rm);
            float corr = __expf(m_st[qt] - mnew);
            m_st[qt] = mnew;
            float ps = 0.f;
            #pragma unroll
            for (int kt = 0; kt < 4; kt++) {
                union { uint2 u; short s[4]; } pk;
                #pragma unroll
                for (int r = 0; r < 4; r++) {
                    float p = __expf(sc[kt][qt][r] - mnew);
                    ps += p;
                    pk.s[r] = f2bf_s(p);
                }
                // P[query][key], keys kt*16+quad*4..+3; seg swizzle on query row bits
                *(uint2*)&myP[(qt * 16 + l16) * 64 +
                              (((kt * 2 + (quad >> 1)) ^ (l16 & 7)) * 8) + (quad & 1) * 4] = pk.u;
            }
            ps += __shfl_xor(ps, 16);
            ps += __shfl_xor(ps, 32);
            l_st[qt] = l_st[qt] * corr + ps;
            #pragma unroll
            for (int dt = 0; dt < 4; dt++) accO[dt][qt] *= corr;
        }
        asm volatile("" ::: "memory");   // keep pf reads after P writes (same-wave DS is in-order)
        // PV: O^T += V^T @ P^T  (B-frag = P rows)
        #pragma unroll
        for (int qt = 0; qt < 4; qt++) {
            bf16x8 pf0 = *(bf16x8*)&myP[(qt * 16 + l16) * 64 + ((quad ^ (l16 & 7)) * 8)];
            bf16x8 pf1 = *(bf16x8*)&myP[(qt * 16 + l16) * 64 + (((4 + quad) ^ (l16 & 7)) * 8)];
            #pragma unroll
            for (int dt = 0; dt < 4; dt++) {
                accO[dt][qt] = __builtin_amdgcn_mfma_f32_16x16x32_bf16(vf[dt][0], pf0, accO[dt][qt], 0, 0, 0);
                accO[dt][qt] = __builtin_amdgcn_mfma_f32_16x16x32_bf16(vf[dt][1], pf1, accO[dt][qt], 0, 0, 0);
            }
        }
        __syncthreads();   // all waves done with sK/sVT -> next staging safe
    }

    // epilogue: O = O^T / l, pack 4 consecutive dims per b64 store
    #pragma unroll
    for (int qt = 0; qt < 4; qt++) {
        float inv = 1.f / l_st[qt];
        int row = qb0 + qt * 16 + l16;
        __hip_bfloat16* orow = ao + ((size_t)(b * SEQ + row)) * D_MODEL + hh * HS;
        #pragma unroll
        for (int dt = 0; dt < 4; dt++) {
            union { uint2 u; short s[4]; } pk;
            #pragma unroll
            for (int r = 0; r < 4; r++) pk.s[r] = f2bf_s(accO[dt][qt][r] * inv);
            *(uint2*)(orow + dt * 16 + quad * 4) = pk.u;
        }
    }
}

// ---------------------------------------------------------------- head FC1: (8,768)@(768,3072)+relu
__global__ __launch_bounds__(256) void fc1_kernel(
    const float* __restrict__ A, const float* __restrict__ W,
    const float* __restrict__ bias, float* __restrict__ out)
{
    __shared__ float sa[D_MODEL];
    int row = blockIdx.x, t = threadIdx.x;
    for (int i = t; i < D_MODEL; i += 256) sa[i] = A[(size_t)row * D_MODEL + i];
    __syncthreads();
    int col = blockIdx.y * 256 + t;
    float s = 0.f;
    #pragma unroll 8
    for (int kk = 0; kk < D_MODEL; kk++) s = fmaf(sa[kk], W[(size_t)kk * DFF + col], s);
    s += bias[col];
    out[(size_t)row * DFF + col] = fmaxf(s, 0.f);
}

// ---------------------------------------------------------------- head FC2: (8,3072)@(3072,16)
__global__ __launch_bounds__(256) void fc2_kernel(
    const float* __restrict__ A, const float* __restrict__ W,
    const float* __restrict__ bias, float* __restrict__ out)
{
    __shared__ float wred[4][NCLS];
    int row = blockIdx.x, t = threadIdx.x;
    int wave = t >> 6, lane = t & 63;
    const float* a = A + (size_t)row * DFF;
    float acc[NCLS];
    #pragma unroll
    for (int c = 0; c < NCLS; c++) acc[c] = 0.f;
    for (int kk = t; kk < DFF; kk += 256) {
        float av = a[kk];
        const float4* wr = (const float4*)(W + (size_t)kk * NCLS);
        float4 w0 = wr[0], w1 = wr[1], w2 = wr[2], w3 = wr[3];
        acc[0]  = fmaf(av, w0.x, acc[0]);  acc[1]  = fmaf(av, w0.y, acc[1]);
        acc[2]  = fmaf(av, w0.z, acc[2]);  acc[3]  = fmaf(av, w0.w, acc[3]);
        acc[4]  = fmaf(av, w1.x, acc[4]);  acc[5]  = fmaf(av, w1.y, acc[5]);
        acc[6]  = fmaf(av, w1.z, acc[6]);  acc[7]  = fmaf(av, w1.w, acc[7]);
        acc[8]  = fmaf(av, w2.x, acc[8]);  acc[9]  = fmaf(av, w2.y, acc[9]);
        acc[10] = fmaf(av, w2.z, acc[10]); acc[11] = fmaf(av, w2.w, acc[11]);
        acc[12] = fmaf(av, w3.x, acc[12]); acc[13] = fmaf(av, w3.y, acc[13]);
        acc[14] = fmaf(av, w3.z, acc[14]); acc[15] = fmaf(av, w3.w, acc[15]);
    }
    #pragma unroll
    for (int c = 0; c < NCLS; c++)
        #pragma unroll
        for (int off = 32; off; off >>= 1) acc[c] += __shfl_down(acc[c], off);
    if (lane == 0)
        #pragma unroll
        for (int c = 0; c < NCLS; c++) wred[wave][c] = acc[c];
    __syncthreads();
    if (t < NCLS)
        out[row * NCLS + t] = wred[0][t] + wred[1][t] + wred[2][t] + wred[3][t] + bias[t];
}

// ---------------------------------------------------------------- launch
extern "C" void kernel_launch(void* const* d_in, const int* in_sizes, int n_in,
                              void* d_out, int out_size, void* d_ws, size_t ws_size,
                              hipStream_t stream)
{
    const int*   x     = (const int*)  d_in[0];
    const int*   amask = (const int*)  d_in[1];
    const float* tok   = (const float*)d_in[2];
    const float* pos   = (const float*)d_in[3];
    const float* Wq    = (const float*)d_in[4];
    const float* Wk    = (const float*)d_in[5];
    const float* Wv    = (const float*)d_in[6];
    const float* Wo    = (const float*)d_in[7];
    const float* bo    = (const float*)d_in[8];
    const float* ln1w  = (const float*)d_in[9];
    const float* ln1b  = (const float*)d_in[10];
    const float* ln2w  = (const float*)d_in[11];
    const float* ln2b  = (const float*)d_in[12];
    const float* W1    = (const float*)d_in[13];
    const float* b1    = (const float*)d_in[14];
    const float* W2    = (const float*)d_in[15];
    const float* b2    = (const float*)d_in[16];
    const float* lnfw  = (const float*)d_in[17];
    const float* lnfb  = (const float*)d_in[18];
    const float* cW1   = (const float*)d_in[19];
    const float* cb1   = (const float*)d_in[20];
    const float* cW2   = (const float*)d_in[21];
    const float* cb2   = (const float*)d_in[22];

    char* base = (char*)d_ws;
    const size_t MD = (size_t)MROWS * D_MODEL;
    float* h = (float*)base;                         base += MD * 4;
    __hip_bfloat16* xn = (__hip_bfloat16*)base;      base += MD * 2;
    __hip_bfloat16* qb = (__hip_bfloat16*)base;      base += MD * 2;
    __hip_bfloat16* kb = (__hip_bfloat16*)base;      base += MD * 2;
    __hip_bfloat16* vb = (__hip_bfloat16*)base;      base += MD * 2;
    __hip_bfloat16* vT = (__hip_bfloat16*)base;      base += MD * 2;
    __hip_bfloat16* ff = (__hip_bfloat16*)base;      base += (size_t)MROWS * DFF * 2;
    float* lnf = (float*)base;                       base += (size_t)NB * D_MODEL * 4;
    float* cls = (float*)base;                       base += (size_t)NB * DFF * 4;
    __hip_bfloat16* wQKV = (__hip_bfloat16*)base;    base += (size_t)NLAYER * 3 * D_MODEL * D_MODEL * 2;
    __hip_bfloat16* wTo = (__hip_bfloat16*)base;     base += (size_t)NLAYER * D_MODEL * D_MODEL * 2;
    __hip_bfloat16* wT1 = (__hip_bfloat16*)base;     base += (size_t)NLAYER * D_MODEL * DFF * 2;
    __hip_bfloat16* wT2 = (__hip_bfloat16*)base;     base += (size_t)NLAYER * DFF * D_MODEL * 2;

    const size_t SQW = (size_t)D_MODEL * D_MODEL;
    const size_t SFF = (size_t)D_MODEL * DFF;

    convw_kernel<1><<<dim3(12,12,4), 256, 0, stream>>>(Wq, wQKV + 0 * SQW, D_MODEL, D_MODEL, SQW, 3 * SQW);
    convw_kernel<1><<<dim3(12,12,4), 256, 0, stream>>>(Wk, wQKV + 1 * SQW, D_MODEL, D_MODEL, SQW, 3 * SQW);
    convw_kernel<1><<<dim3(12,12,4), 256, 0, stream>>>(Wv, wQKV + 2 * SQW, D_MODEL, D_MODEL, SQW, 3 * SQW);
    convw_kernel<0><<<dim3(12,12,4), 256, 0, stream>>>(Wo, wTo, D_MODEL, D_MODEL, SQW, SQW);
    convw_kernel<0><<<dim3(12,48,4), 256, 0, stream>>>(W1, wT1, D_MODEL, DFF, SFF, SFF);
    convw_kernel<0><<<dim3(48,12,4), 256, 0, stream>>>(W2, wT2, DFF, D_MODEL, SFF, SFF);

    embed_kernel<<<MROWS, 256, 0, stream>>>(x, tok, pos, h);

    dim3 gQKV(MROWS / 128, (3 * D_MODEL) / 128);
    dim3 gD(MROWS / 128, D_MODEL / 128);
    dim3 gF(MROWS / 128, DFF / 128);
    for (int l = 0; l < NLAYER; l++) {
        ln_kernel<1><<<MROWS, 256, 0, stream>>>(h, ln1w + l * D_MODEL, ln1b + l * D_MODEL, xn, 1, 0);
        gemm128<1><<<gQKV, 256, 0, stream>>>(xn, wQKV + l * 3 * SQW, nullptr, nullptr, qb, MROWS, 3 * D_MODEL, D_MODEL, 0);
        vtrans_kernel<<<dim3(NB * NHEAD, SEQ / 64), 256, 0, stream>>>(vb, vT);
        attn_mfma_kernel<<<NB * NHEAD * 8, 128, 0, stream>>>(qb, kb, vT, amask, xn);
        gemm128<0><<<gD, 256, 0, stream>>>(xn, wTo + l * SQW, bo + l * D_MODEL, h, h, MROWS, D_MODEL, D_MODEL, 0);
        ln_kernel<1><<<MROWS, 256, 0, stream>>>(h, ln2w + l * D_MODEL, ln2b + l * D_MODEL, xn, 1, 0);
        gemm128<2><<<gF, 256, 0, stream>>>(xn, wT1 + l * SFF, b1 + l * DFF, nullptr, ff, MROWS, DFF, D_MODEL, 1);
        gemm128<0><<<gD, 256, 0, stream>>>(ff, wT2 + l * SFF, b2 + l * D_MODEL, h, h, MROWS, D_MODEL, DFF, 0);
    }
    ln_kernel<0><<<NB, 256, 0, stream>>>(h, lnfw, lnfb, lnf, SEQ, SEQ - 1);
    fc1_kernel<<<dim3(NB, DFF / 256), 256, 0, stream>>>(lnf, cW1, cb1, cls);
    fc2_kernel<<<NB, 256, 0, stream>>>(cls, cW2, cb2, (float*)d_out);
}